// Round 7
// baseline (1423.413 us; speedup 1.0000x reference)
//
#include <hip/hip_runtime.h>
#include <math.h>

#define TOK 4096
#define HD 512

typedef _Float16 f16x8 __attribute__((ext_vector_type(8)));
typedef float f32x4 __attribute__((ext_vector_type(4)));

__device__ __forceinline__ float gelu_f(float x) {
    return 0.5f * x * (1.0f + erff(x * 0.70710678118654752f));
}

__device__ __forceinline__ void gload16(const void* g, void* l) {
    __builtin_amdgcn_global_load_lds((const __attribute__((address_space(1))) void*)g,
                                     (__attribute__((address_space(3))) void*)l, 16, 0, 0);
}

__device__ __forceinline__ void split2(float v, _Float16& h, _Float16& l) {
    h = (_Float16)v;
    l = (_Float16)(v - (float)h);
}

// ------------------------------------------------------------------
// fp32 -> (hi,lo) fp16, 8 elems/thread. grid = numel/2048
// ------------------------------------------------------------------
__global__ __launch_bounds__(256)
void split_x_kernel(const float* __restrict__ in, _Float16* __restrict__ hi,
                    _Float16* __restrict__ lo)
{
    const size_t idx = (size_t)blockIdx.x * 256 + threadIdx.x;
    const float4 v0 = *(const float4*)(in + idx * 8);
    const float4 v1 = *(const float4*)(in + idx * 8 + 4);
    float vv[8] = {v0.x, v0.y, v0.z, v0.w, v1.x, v1.y, v1.z, v1.w};
    f16x8 h, l;
    #pragma unroll
    for (int j = 0; j < 8; ++j) {
        _Float16 a, b; split2(vv[j], a, b);
        h[j] = a; l[j] = b;
    }
    *(f16x8*)(hi + idx * 8) = h;
    *(f16x8*)(lo + idx * 8) = l;
}

// ------------------------------------------------------------------
// Weight prep: [Ktot][512] fp32 row-major -> frag layout [Ktot/8][512][8]
// hi/lo fp16 (8 = k-minor). grid = Ktot*512/2048 blocks.
// ------------------------------------------------------------------
__global__ __launch_bounds__(256)
void split_w_kernel(const float* __restrict__ w, _Float16* __restrict__ hi,
                    _Float16* __restrict__ lo)
{
    const int idx = blockIdx.x * 256 + threadIdx.x;
    const int kbG = idx >> 9, n = idx & 511;
    const float* src = w + (((size_t)kbG * 8) << 9) + n;
    f16x8 h, l;
    #pragma unroll
    for (int j = 0; j < 8; ++j) {
        const float v = src[(size_t)j << 9];
        _Float16 a, b; split2(v, a, b);
        h[j] = a; l[j] = b;
    }
    *(f16x8*)(hi + (size_t)idx * 8) = h;
    *(f16x8*)(lo + (size_t)idx * 8) = l;
}

// ------------------------------------------------------------------
// Split-fp16 MFMA GEMM: out[M=4096][512] = act(A[M][K] @ Bfrag + bias)
// OSPL: 0 = fp32 out; 1 = split fp16 out; 2 = score mode (atomicAdd
//       sum(gelu(v)*sw2[n]) into mlog4[m*4]).
// ------------------------------------------------------------------
template<int ACT, int OSPL>
__global__ __launch_bounds__(256, 2)
void gemm_hh(const _Float16* __restrict__ ah, const _Float16* __restrict__ al,
             const _Float16* __restrict__ bh, const _Float16* __restrict__ bl,
             const float* __restrict__ bias, int K,
             float* __restrict__ outF,
             _Float16* __restrict__ oh, _Float16* __restrict__ ol,
             const float* __restrict__ sw2, float* __restrict__ mlog4)
{
    __shared__ _Float16 Ah[2][2048], Al[2][2048];
    const int tid = threadIdx.x;
    const int l = tid & 63, w = tid >> 6;
    const int kb = l >> 4, lr = l & 15;
    const int m0 = blockIdx.y << 6;
    const int wn0 = (blockIdx.x << 7) + (w << 5);
    const int scr = tid & 63, sckb = tid >> 6;
    const int sbase = (tid & 192) * 8;

    f32x4 acc[4][2];
    #pragma unroll
    for (int i = 0; i < 4; ++i)
        #pragma unroll
        for (int j = 0; j < 2; ++j) acc[i][j] = (f32x4){0.f, 0.f, 0.f, 0.f};

    {
        const size_t ga = (size_t)(m0 + scr) * K + sckb * 8;
        gload16(ah + ga, Ah[0] + sbase);
        gload16(al + ga, Al[0] + sbase);
    }
    int cur = 0;
    for (int k0 = 0; k0 < K; k0 += 32) {
        __syncthreads();
        if (k0 + 32 < K) {
            const size_t ga = (size_t)(m0 + scr) * K + k0 + 32 + sckb * 8;
            gload16(ah + ga, Ah[cur ^ 1] + sbase);
            gload16(al + ga, Al[cur ^ 1] + sbase);
        }
        f16x8 fah[4], fal[4];
        #pragma unroll
        for (int i = 0; i < 4; ++i) {
            const int off = (kb * 64 + i * 16 + lr) * 8;
            fah[i] = *(const f16x8*)(Ah[cur] + off);
            fal[i] = *(const f16x8*)(Al[cur] + off);
        }
        #pragma unroll
        for (int j = 0; j < 2; ++j) {
            const size_t gb = ((size_t)(((k0 >> 3) + kb) << 9) + wn0 + j * 16 + lr) * 8;
            const f16x8 fbh = *(const f16x8*)(bh + gb);
            const f16x8 fbl = *(const f16x8*)(bl + gb);
            #pragma unroll
            for (int i = 0; i < 4; ++i) {
                acc[i][j] = __builtin_amdgcn_mfma_f32_16x16x32_f16(fah[i], fbh, acc[i][j], 0, 0, 0);
                acc[i][j] = __builtin_amdgcn_mfma_f32_16x16x32_f16(fah[i], fbl, acc[i][j], 0, 0, 0);
                acc[i][j] = __builtin_amdgcn_mfma_f32_16x16x32_f16(fal[i], fbh, acc[i][j], 0, 0, 0);
            }
        }
        cur ^= 1;
    }
    #pragma unroll
    for (int i = 0; i < 4; ++i) {
        float sacc[4] = {0.f, 0.f, 0.f, 0.f};
        #pragma unroll
        for (int j = 0; j < 2; ++j) {
            const int n = wn0 + j * 16 + lr;
            const float bv = bias[n];
            const float swv = (OSPL == 2) ? sw2[n] : 0.f;
            #pragma unroll
            for (int r = 0; r < 4; ++r) {
                const int m = m0 + i * 16 + (kb << 2) + r;
                float v = acc[i][j][r] + bv;
                if (ACT) v = gelu_f(v);
                if (OSPL == 2) {
                    sacc[r] = fmaf(v, swv, sacc[r]);
                } else if (OSPL == 1) {
                    _Float16 vh, vl; split2(v, vh, vl);
                    oh[((size_t)m << 9) + n] = vh;
                    ol[((size_t)m << 9) + n] = vl;
                } else {
                    outF[((size_t)m << 9) + n] = v;
                }
            }
        }
        if (OSPL == 2) {
            #pragma unroll
            for (int r = 0; r < 4; ++r) {
                float s = sacc[r];
                s += __shfl_xor(s, 1, 64);
                s += __shfl_xor(s, 2, 64);
                s += __shfl_xor(s, 4, 64);
                s += __shfl_xor(s, 8, 64);
                if (lr == 0) {
                    const int m = m0 + i * 16 + (kb << 2) + r;
                    atomicAdd(&mlog4[m << 2], s);
                }
            }
        }
    }
}

// ------------------------------------------------------------------
// Fused expert, 512 threads, n-slice halved for occupancy.
// grid = (64, 8), y = expert (expert-major keeps weights L2-hot; R5
// showed interleaving experts thrashes L2 -> 2.3 GB fetch).
// Per half ns in {0,256}:
//   stage1: Hslice = gelu(X@W1e[:,ns:ns+256]+b)*rw -> LDS split-fp16
//           subtiled [32 kgrp][64 row][8]  (64 KB)
//   stage2: acc2 += Hslice @ W2e[ns:ns+256, :]   (full 64x512 in regs)
// LDS total = 64 KB H + 16 KB X dbuf = 80 KB -> 2 blocks/CU, 16 waves.
// ------------------------------------------------------------------
__global__ __launch_bounds__(512, 4)
void fused_expert4(const _Float16* __restrict__ xh, const _Float16* __restrict__ xl,
                   const _Float16* __restrict__ w1h, const _Float16* __restrict__ w1l,
                   const _Float16* __restrict__ w2h, const _Float16* __restrict__ w2l,
                   const float* __restrict__ eb1, const float* __restrict__ rw,
                   float* __restrict__ mixed)
{
    __shared__ _Float16 Hh[16384], Hl[16384];     // [32 kgrp][64 row][8] = 32 KB each
    __shared__ _Float16 Xh[2][2048], Xl[2][2048]; // 16 KB
    const int tid = threadIdx.x;
    const int w = tid >> 6, l = tid & 63;
    const int kb = l >> 4, lr = l & 15;
    const int e = blockIdx.y;
    const int m0 = blockIdx.x << 6;
    const int wm = w >> 2, wn = w & 3;            // 2m x 4n wave grid
    const int sw = w & 3;
    const int sbase = sw << 9;

    const _Float16* w1he = w1h + ((size_t)e << 18);
    const _Float16* w1le = w1l + ((size_t)e << 18);
    const _Float16* w2he = w2h + ((size_t)e << 18);
    const _Float16* w2le = w2l + ((size_t)e << 18);

    f32x4 acc2[2][8];
    #pragma unroll
    for (int i = 0; i < 2; ++i)
        #pragma unroll
        for (int j = 0; j < 8; ++j) acc2[i][j] = (f32x4){0.f, 0.f, 0.f, 0.f};

    for (int ns = 0; ns < 512; ns += 256) {
        // ---- stage 1: acc1 = X @ W1e[:, ns..ns+256) ----
        f32x4 acc1[2][4];
        #pragma unroll
        for (int i = 0; i < 2; ++i)
            #pragma unroll
            for (int j = 0; j < 4; ++j) acc1[i][j] = (f32x4){0.f, 0.f, 0.f, 0.f};
        {
            const size_t ga = ((size_t)(m0 + l) << 9) + (sw << 3);
            if (tid < 256) gload16(xh + ga, Xh[0] + sbase);
            else           gload16(xl + ga, Xl[0] + sbase);
        }
        int cur = 0;
        for (int k0 = 0; k0 < 512; k0 += 32) {
            __syncthreads();
            if (k0 + 32 < 512) {
                const size_t ga = ((size_t)(m0 + l) << 9) + k0 + 32 + (sw << 3);
                if (tid < 256) gload16(xh + ga, Xh[cur ^ 1] + sbase);
                else           gload16(xl + ga, Xl[cur ^ 1] + sbase);
            }
            f16x8 fah[2], fal[2];
            #pragma unroll
            for (int i = 0; i < 2; ++i) {
                const int off = (kb * 64 + wm * 32 + i * 16 + lr) * 8;
                fah[i] = *(const f16x8*)(Xh[cur] + off);
                fal[i] = *(const f16x8*)(Xl[cur] + off);
            }
            #pragma unroll
            for (int j = 0; j < 4; ++j) {
                const int n = ns + wn * 64 + j * 16 + lr;
                const size_t gb = ((size_t)(((k0 >> 3) + kb) << 9) + n) * 8;
                const f16x8 fbh = *(const f16x8*)(w1he + gb);
                const f16x8 fbl = *(const f16x8*)(w1le + gb);
                #pragma unroll
                for (int i = 0; i < 2; ++i) {
                    acc1[i][j] = __builtin_amdgcn_mfma_f32_16x16x32_f16(fah[i], fbh, acc1[i][j], 0, 0, 0);
                    acc1[i][j] = __builtin_amdgcn_mfma_f32_16x16x32_f16(fah[i], fbl, acc1[i][j], 0, 0, 0);
                    acc1[i][j] = __builtin_amdgcn_mfma_f32_16x16x32_f16(fal[i], fbh, acc1[i][j], 0, 0, 0);
                }
            }
            cur ^= 1;
        }
        // ---- epilogue 1: gelu+bias+route-scale -> H slice (split fp16) ----
        __syncthreads();   // all waves done reading X & (prev half's) H
        #pragma unroll
        for (int i = 0; i < 2; ++i)
            #pragma unroll
            for (int j = 0; j < 4; ++j) {
                const int nl = wn * 64 + j * 16 + lr;          // 0..255 in slice
                const float bv = eb1[(e << 9) + ns + nl];
                #pragma unroll
                for (int r = 0; r < 4; ++r) {
                    const int ri = wm * 32 + i * 16 + (kb << 2) + r;
                    const float v = gelu_f(acc1[i][j][r] + bv) * rw[((size_t)(m0 + ri) << 3) + e];
                    _Float16 vh, vl; split2(v, vh, vl);
                    const int off = ((nl >> 3) * 64 + ri) * 8 + (nl & 7);
                    Hh[off] = vh; Hl[off] = vl;
                }
            }
        __syncthreads();

        // ---- stage 2: acc2 += Hslice @ W2e[ns..ns+256, :] ----
        for (int k0 = 0; k0 < 256; k0 += 32) {
            f16x8 fah[2], fal[2];
            #pragma unroll
            for (int i = 0; i < 2; ++i) {
                const int off = (((k0 >> 3) + kb) * 64 + wm * 32 + i * 16 + lr) * 8;
                fah[i] = *(const f16x8*)(Hh + off);
                fal[i] = *(const f16x8*)(Hl + off);
            }
            #pragma unroll
            for (int j = 0; j < 8; ++j) {
                const int n = wn * 128 + j * 16 + lr;
                const size_t gb = ((size_t)(((ns + k0) >> 3) + kb) << 9) * 8 + (size_t)n * 8;
                const f16x8 fbh = *(const f16x8*)(w2he + gb);
                const f16x8 fbl = *(const f16x8*)(w2le + gb);
                #pragma unroll
                for (int i = 0; i < 2; ++i) {
                    acc2[i][j] = __builtin_amdgcn_mfma_f32_16x16x32_f16(fah[i], fbh, acc2[i][j], 0, 0, 0);
                    acc2[i][j] = __builtin_amdgcn_mfma_f32_16x16x32_f16(fah[i], fbl, acc2[i][j], 0, 0, 0);
                    acc2[i][j] = __builtin_amdgcn_mfma_f32_16x16x32_f16(fal[i], fbh, acc2[i][j], 0, 0, 0);
                }
            }
        }
        __syncthreads();   // stage-2 H reads done before next half's writes
    }
    #pragma unroll
    for (int i = 0; i < 2; ++i)
        #pragma unroll
        for (int j = 0; j < 8; ++j) {
            const int n = wn * 128 + j * 16 + lr;
            #pragma unroll
            for (int r = 0; r < 4; ++r) {
                const int m = m0 + wm * 32 + i * 16 + (kb << 2) + r;
                atomicAdd(&mixed[((size_t)m << 9) + n], acc2[i][j][r]);
            }
        }
}

// ------------------------------------------------------------------
// mixed init: mixed[m][n] = sum_e rw[m][e] * eb2[e][n]. grid = 2048
// ------------------------------------------------------------------
__global__ __launch_bounds__(256)
void init_mixed(const float* __restrict__ rw, const float* __restrict__ eb2,
                float* __restrict__ mixed)
{
    const int idx = blockIdx.x * 256 + threadIdx.x;
    const int m = idx >> 7, n4 = (idx & 127) << 2;
    float rwv[8];
    #pragma unroll
    for (int e = 0; e < 8; ++e) rwv[e] = rw[(m << 3) + e];
    float4 o = {0.f, 0.f, 0.f, 0.f};
    #pragma unroll
    for (int e = 0; e < 8; ++e) {
        const float4 b = *(const float4*)(eb2 + (e << 9) + n4);
        o.x = fmaf(rwv[e], b.x, o.x); o.y = fmaf(rwv[e], b.y, o.y);
        o.z = fmaf(rwv[e], b.z, o.z); o.w = fmaf(rwv[e], b.w, o.w);
    }
    *(float4*)(mixed + ((size_t)m << 9) + n4) = o;
}

// ------------------------------------------------------------------
// Router softmax
// ------------------------------------------------------------------
__global__ __launch_bounds__(256)
void router_kernel(const float* __restrict__ t,
                   const float* __restrict__ rw2,
                   const float* __restrict__ rb2,
                   float* __restrict__ route_w)
{
    __shared__ float s[512 * 9];
    const int tid = threadIdx.x;
    for (int idx = tid; idx < 4096; idx += 256)
        s[(idx >> 3) * 9 + (idx & 7)] = rw2[idx];
    __syncthreads();
    const int lane = tid & 63;
    const int tok = (blockIdx.x << 2) + (tid >> 6);
    const float* tp = t + ((size_t)tok << 9);
    float acc[8] = {};
    #pragma unroll
    for (int kq = 0; kq < 8; ++kq) {
        const int k = (kq << 6) + lane;
        const float tv = tp[k];
        #pragma unroll
        for (int e = 0; e < 8; ++e)
            acc[e] = fmaf(tv, s[k * 9 + e], acc[e]);
    }
    #pragma unroll
    for (int e = 0; e < 8; ++e)
        #pragma unroll
        for (int off = 32; off; off >>= 1)
            acc[e] += __shfl_xor(acc[e], off, 64);
    float mx = -1e30f;
    #pragma unroll
    for (int e = 0; e < 8; ++e) { acc[e] += rb2[e]; mx = fmaxf(mx, acc[e]); }
    float sum = 0.f;
    #pragma unroll
    for (int e = 0; e < 8; ++e) { acc[e] = expf(acc[e] - mx); sum += acc[e]; }
    const float inv = 1.0f / sum;
    if (lane == 0) {
        #pragma unroll
        for (int e = 0; e < 8; ++e) route_w[(tok << 3) + e] = acc[e] * inv;
    }
}

// ------------------------------------------------------------------
// Final: top-2 + masked softmax + blend + LayerNorm, one block/token.
// ------------------------------------------------------------------
__global__ __launch_bounds__(256)
void final_kernel(const float* __restrict__ mixedb,
                  const float* __restrict__ mlog,
                  const float* __restrict__ sb2,
                  const float* __restrict__ g,
                  const float* __restrict__ bta,
                  float* __restrict__ out)
{
    const int tok = blockIdx.x, tid = threadIdx.x;
    float v[4];
    #pragma unroll
    for (int m = 0; m < 4; ++m) v[m] = mlog[(tok << 2) + m] + sb2[0];
    int i1 = 0;
    #pragma unroll
    for (int m = 1; m < 4; ++m) if (v[m] > v[i1]) i1 = m;
    int i2 = (i1 == 0) ? 1 : 0;
    for (int m = i2 + 1; m < 4; ++m) if (m != i1 && v[m] > v[i2]) i2 = m;
    const float e2 = expf(v[i2] - v[i1]);
    const float winv = 1.0f / (1.0f + e2);
    const float w1 = winv, w2 = e2 * winv;
    const float* p1 = mixedb + (((size_t)i1 * TOK + tok) << 9);
    const float* p2 = mixedb + (((size_t)i2 * TOK + tok) << 9);
    const int h0 = tid, h1 = tid + 256;
    const float c0 = w1 * p1[h0] + w2 * p2[h0];
    const float c1 = w1 * p1[h1] + w2 * p2[h1];
    float s = c0 + c1, sq = c0 * c0 + c1 * c1;
    #pragma unroll
    for (int off = 32; off; off >>= 1) {
        s += __shfl_xor(s, off, 64);
        sq += __shfl_xor(sq, off, 64);
    }
    __shared__ float red[8];
    const int wv = tid >> 6, ln = tid & 63;
    if (ln == 0) { red[wv] = s; red[4 + wv] = sq; }
    __syncthreads();
    s = red[0] + red[1] + red[2] + red[3];
    sq = red[4] + red[5] + red[6] + red[7];
    const float mu = s * (1.0f / 512.0f);
    const float var = sq * (1.0f / 512.0f) - mu * mu;
    const float r = 1.0f / sqrtf(var + 1e-5f);
    out[((size_t)tok << 9) + h0] = (c0 - mu) * r * g[h0] + bta[h0];
    out[((size_t)tok << 9) + h1] = (c1 - mu) * r * g[h1] + bta[h1];
}

extern "C" void kernel_launch(void* const* d_in, const int* in_sizes, int n_in,
                              void* d_out, int out_size, void* d_ws, size_t ws_size,
                              hipStream_t stream)
{
    (void)in_sizes; (void)n_in; (void)out_size; (void)ws_size;
    const float* ew1  = (const float*)d_in[12];
    const float* eb1  = (const float*)d_in[13];
    const float* ew2  = (const float*)d_in[14];
    const float* eb2  = (const float*)d_in[15];
    const float* rw1  = (const float*)d_in[16];
    const float* rb1  = (const float*)d_in[17];
    const float* rw2  = (const float*)d_in[18];
    const float* rb2  = (const float*)d_in[19];
    const float* sw1  = (const float*)d_in[20];
    const float* sb1  = (const float*)d_in[21];
    const float* sw2  = (const float*)d_in[22];
    const float* sb2  = (const float*)d_in[23];
    const float* ln_g = (const float*)d_in[24];
    const float* ln_b = (const float*)d_in[25];
    const int KD[4] = {1024, 64, 768, 512};

    // ---- workspace layout ----
    char* p = (char*)d_ws;
    auto alloc = [&](size_t bytes) {
        void* r = (void*)p;
        p += (bytes + 255) & ~(size_t)255;
        return r;
    };
    float*     mixedb  = (float*)alloc((size_t)4 * TOK * HD * 4);
    float*     scratch = (float*)alloc((size_t)TOK * HD * 4);   // t
    float*     route_w = (float*)alloc((size_t)TOK * 8 * 4);
    float*     mlog    = (float*)alloc((size_t)TOK * 4 * 4);
    _Float16*  xh      = (_Float16*)alloc((size_t)TOK * HD * 2);
    _Float16*  xl      = (_Float16*)alloc((size_t)TOK * HD * 2);
    _Float16*  mxh     = (_Float16*)alloc((size_t)TOK * HD * 2);
    _Float16*  mxl     = (_Float16*)alloc((size_t)TOK * HD * 2);
    _Float16*  fh      = (_Float16*)alloc((size_t)TOK * 1024 * 2);
    _Float16*  fl      = (_Float16*)alloc((size_t)TOK * 1024 * 2);
    _Float16*  pwh     = (_Float16*)alloc((size_t)1024 * HD * 2);
    _Float16*  pwl     = (_Float16*)alloc((size_t)1024 * HD * 2);
    _Float16*  rw1h    = (_Float16*)alloc((size_t)HD * HD * 2);
    _Float16*  rw1l    = (_Float16*)alloc((size_t)HD * HD * 2);
    _Float16*  sw1h    = (_Float16*)alloc((size_t)HD * HD * 2);
    _Float16*  sw1l    = (_Float16*)alloc((size_t)HD * HD * 2);
    _Float16*  w1h     = (_Float16*)alloc((size_t)8 * HD * HD * 2);
    _Float16*  w1l     = (_Float16*)alloc((size_t)8 * HD * HD * 2);
    _Float16*  w2h     = (_Float16*)alloc((size_t)8 * HD * HD * 2);
    _Float16*  w2l     = (_Float16*)alloc((size_t)8 * HD * HD * 2);

    // mlog accumulated via atomics -> zero it (ws is re-poisoned every call)
    hipMemsetAsync(mlog, 0, (size_t)TOK * 4 * sizeof(float), stream);

    // ---- weight prep (frag layout splits) ----
    split_w_kernel<<<dim3(1024), 256, 0, stream>>>(ew1, w1h, w1l);
    split_w_kernel<<<dim3(1024), 256, 0, stream>>>(ew2, w2h, w2l);
    split_w_kernel<<<dim3(128), 256, 0, stream>>>(rw1, rw1h, rw1l);
    split_w_kernel<<<dim3(128), 256, 0, stream>>>(sw1, sw1h, sw1l);

    for (int mod = 0; mod < 4; ++mod) {
        const float* feat = (const float*)d_in[mod * 3 + 0];
        const float* pw   = (const float*)d_in[mod * 3 + 1];
        const float* pb   = (const float*)d_in[mod * 3 + 2];
        float* mixm = mixedb + (size_t)mod * TOK * HD;
        const int K = KD[mod];

        // splits for this modality
        split_x_kernel<<<dim3(TOK * K / 2048), 256, 0, stream>>>(feat, fh, fl);
        split_w_kernel<<<dim3(K / 4), 256, 0, stream>>>(pw, pwh, pwl);
        // x = feat @ pw + pb  -> xh/xl
        gemm_hh<0, 1><<<dim3(4, 64), 256, 0, stream>>>(
            fh, fl, pwh, pwl, pb, K, nullptr, xh, xl, nullptr, nullptr);
        // t = gelu(x @ rw1 + rb1)
        gemm_hh<1, 0><<<dim3(4, 64), 256, 0, stream>>>(
            xh, xl, rw1h, rw1l, rb1, HD, scratch, nullptr, nullptr, nullptr, nullptr);
        // route_w = softmax(t @ rw2 + rb2)
        router_kernel<<<dim3(TOK / 4), 256, 0, stream>>>(scratch, rw2, rb2, route_w);
        // mixed = sum_e rw*eb2, then fused experts accumulate
        init_mixed<<<dim3(TOK * HD / 4 / 256), 256, 0, stream>>>(route_w, eb2, mixm);
        fused_expert4<<<dim3(64, 8), 512, 0, stream>>>(
            xh, xl, w1h, w1l, w2h, w2l, eb1, route_w, mixm);
        // u = gelu(mixed @ sw1 + sb1); score fused into epilogue -> mlog
        split_x_kernel<<<dim3(TOK * HD / 2048), 256, 0, stream>>>(mixm, mxh, mxl);
        gemm_hh<1, 2><<<dim3(4, 64), 256, 0, stream>>>(
            mxh, mxl, sw1h, sw1l, sb1, HD, nullptr, nullptr, nullptr,
            sw2, mlog + mod);
    }
    final_kernel<<<dim3(TOK), 256, 0, stream>>>(mixedb, mlog, sb2, ln_g, ln_b, (float*)d_out);
}

// Round 8
// 1361.582 us; speedup vs baseline: 1.0454x; 1.0454x over previous
//
#include <hip/hip_runtime.h>
#include <math.h>

#define TOK 4096
#define HD 512

typedef _Float16 f16x8 __attribute__((ext_vector_type(8)));
typedef float f32x4 __attribute__((ext_vector_type(4)));

__device__ __forceinline__ float gelu_f(float x) {
    return 0.5f * x * (1.0f + erff(x * 0.70710678118654752f));
}

__device__ __forceinline__ void gload16(const void* g, void* l) {
    __builtin_amdgcn_global_load_lds((const __attribute__((address_space(1))) void*)g,
                                     (__attribute__((address_space(3))) void*)l, 16, 0, 0);
}

__device__ __forceinline__ void split2(float v, _Float16& h, _Float16& l) {
    h = (_Float16)v;
    l = (_Float16)(v - (float)h);
}

// ------------------------------------------------------------------
// fp32 -> (hi,lo) fp16, 8 elems/thread. grid = numel/2048
// ------------------------------------------------------------------
__global__ __launch_bounds__(256)
void split_x_kernel(const float* __restrict__ in, _Float16* __restrict__ hi,
                    _Float16* __restrict__ lo)
{
    const size_t idx = (size_t)blockIdx.x * 256 + threadIdx.x;
    const float4 v0 = *(const float4*)(in + idx * 8);
    const float4 v1 = *(const float4*)(in + idx * 8 + 4);
    float vv[8] = {v0.x, v0.y, v0.z, v0.w, v1.x, v1.y, v1.z, v1.w};
    f16x8 h, l;
    #pragma unroll
    for (int j = 0; j < 8; ++j) {
        _Float16 a, b; split2(vv[j], a, b);
        h[j] = a; l[j] = b;
    }
    *(f16x8*)(hi + idx * 8) = h;
    *(f16x8*)(lo + idx * 8) = l;
}

// ------------------------------------------------------------------
// Weight prep: [Ktot][512] fp32 row-major -> frag layout [Ktot/8][512][8]
// hi/lo fp16 (8 = k-minor). grid = Ktot*512/2048 blocks.
// ------------------------------------------------------------------
__global__ __launch_bounds__(256)
void split_w_kernel(const float* __restrict__ w, _Float16* __restrict__ hi,
                    _Float16* __restrict__ lo)
{
    const int idx = blockIdx.x * 256 + threadIdx.x;
    const int kbG = idx >> 9, n = idx & 511;
    const float* src = w + (((size_t)kbG * 8) << 9) + n;
    f16x8 h, l;
    #pragma unroll
    for (int j = 0; j < 8; ++j) {
        const float v = src[(size_t)j << 9];
        _Float16 a, b; split2(v, a, b);
        h[j] = a; l[j] = b;
    }
    *(f16x8*)(hi + (size_t)idx * 8) = h;
    *(f16x8*)(lo + (size_t)idx * 8) = l;
}

// ------------------------------------------------------------------
// Split-fp16 MFMA GEMM: out[M=4096][512] = act(A[M][K] @ Bfrag + bias)
// OSPL: 0 = fp32 out; 1 = split fp16 out; 2 = score mode (atomicAdd
//       sum(gelu(v)*sw2[n]) into mlog4[m*4]).
// ------------------------------------------------------------------
template<int ACT, int OSPL>
__global__ __launch_bounds__(256, 2)
void gemm_hh(const _Float16* __restrict__ ah, const _Float16* __restrict__ al,
             const _Float16* __restrict__ bh, const _Float16* __restrict__ bl,
             const float* __restrict__ bias, int K,
             float* __restrict__ outF,
             _Float16* __restrict__ oh, _Float16* __restrict__ ol,
             const float* __restrict__ sw2, float* __restrict__ mlog4)
{
    __shared__ _Float16 Ah[2][2048], Al[2][2048];
    const int tid = threadIdx.x;
    const int l = tid & 63, w = tid >> 6;
    const int kb = l >> 4, lr = l & 15;
    const int m0 = blockIdx.y << 6;
    const int wn0 = (blockIdx.x << 7) + (w << 5);
    const int scr = tid & 63, sckb = tid >> 6;
    const int sbase = (tid & 192) * 8;

    f32x4 acc[4][2];
    #pragma unroll
    for (int i = 0; i < 4; ++i)
        #pragma unroll
        for (int j = 0; j < 2; ++j) acc[i][j] = (f32x4){0.f, 0.f, 0.f, 0.f};

    {
        const size_t ga = (size_t)(m0 + scr) * K + sckb * 8;
        gload16(ah + ga, Ah[0] + sbase);
        gload16(al + ga, Al[0] + sbase);
    }
    int cur = 0;
    for (int k0 = 0; k0 < K; k0 += 32) {
        __syncthreads();
        if (k0 + 32 < K) {
            const size_t ga = (size_t)(m0 + scr) * K + k0 + 32 + sckb * 8;
            gload16(ah + ga, Ah[cur ^ 1] + sbase);
            gload16(al + ga, Al[cur ^ 1] + sbase);
        }
        f16x8 fah[4], fal[4];
        #pragma unroll
        for (int i = 0; i < 4; ++i) {
            const int off = (kb * 64 + i * 16 + lr) * 8;
            fah[i] = *(const f16x8*)(Ah[cur] + off);
            fal[i] = *(const f16x8*)(Al[cur] + off);
        }
        #pragma unroll
        for (int j = 0; j < 2; ++j) {
            const size_t gb = ((size_t)(((k0 >> 3) + kb) << 9) + wn0 + j * 16 + lr) * 8;
            const f16x8 fbh = *(const f16x8*)(bh + gb);
            const f16x8 fbl = *(const f16x8*)(bl + gb);
            #pragma unroll
            for (int i = 0; i < 4; ++i) {
                acc[i][j] = __builtin_amdgcn_mfma_f32_16x16x32_f16(fah[i], fbh, acc[i][j], 0, 0, 0);
                acc[i][j] = __builtin_amdgcn_mfma_f32_16x16x32_f16(fah[i], fbl, acc[i][j], 0, 0, 0);
                acc[i][j] = __builtin_amdgcn_mfma_f32_16x16x32_f16(fal[i], fbh, acc[i][j], 0, 0, 0);
            }
        }
        cur ^= 1;
    }
    #pragma unroll
    for (int i = 0; i < 4; ++i) {
        float sacc[4] = {0.f, 0.f, 0.f, 0.f};
        #pragma unroll
        for (int j = 0; j < 2; ++j) {
            const int n = wn0 + j * 16 + lr;
            const float bv = bias[n];
            const float swv = (OSPL == 2) ? sw2[n] : 0.f;
            #pragma unroll
            for (int r = 0; r < 4; ++r) {
                const int m = m0 + i * 16 + (kb << 2) + r;
                float v = acc[i][j][r] + bv;
                if (ACT) v = gelu_f(v);
                if (OSPL == 2) {
                    sacc[r] = fmaf(v, swv, sacc[r]);
                } else if (OSPL == 1) {
                    _Float16 vh, vl; split2(v, vh, vl);
                    oh[((size_t)m << 9) + n] = vh;
                    ol[((size_t)m << 9) + n] = vl;
                } else {
                    outF[((size_t)m << 9) + n] = v;
                }
            }
        }
        if (OSPL == 2) {
            #pragma unroll
            for (int r = 0; r < 4; ++r) {
                float s = sacc[r];
                s += __shfl_xor(s, 1, 64);
                s += __shfl_xor(s, 2, 64);
                s += __shfl_xor(s, 4, 64);
                s += __shfl_xor(s, 8, 64);
                if (lr == 0) {
                    const int m = m0 + i * 16 + (kb << 2) + r;
                    atomicAdd(&mlog4[m << 2], s);
                }
            }
        }
    }
}

// ------------------------------------------------------------------
// Fused expert, 512 threads, full-H (R6 structure) + explicit 1-deep
// register double-buffer for weight fragments (software pipeline).
// grid = (64, 8), y = expert (expert-major: only ~4 experts co-resident,
// keeps weight working set small; R5/R7 showed wider co-residency
// thrashes L2 -> FETCH 174MB-2.3GB).
// Stage 1: H = gelu(X@W1e + b1e)*rw -> LDS split-fp16 [64 kgrp][64 row][8]
// Stage 2: mixed += H @ W2e (atomicAdd; bias via init_mixed).
// LDS 144 KB -> 1 block/CU, 8 waves. Weight frags for k+1 prefetched
// into regs before k's MFMAs (pb[2][8] compile-time indexed).
// ------------------------------------------------------------------
__global__ __launch_bounds__(512, 2)
void fused_expert5(const _Float16* __restrict__ xh, const _Float16* __restrict__ xl,
                   const _Float16* __restrict__ w1h, const _Float16* __restrict__ w1l,
                   const _Float16* __restrict__ w2h, const _Float16* __restrict__ w2l,
                   const float* __restrict__ eb1, const float* __restrict__ rw,
                   float* __restrict__ mixed)
{
    __shared__ _Float16 Hh[32768], Hl[32768];     // [64 kgrp][64 row][8]
    __shared__ _Float16 Xh[2][2048], Xl[2][2048];
    const int tid = threadIdx.x;
    const int w = tid >> 6, l = tid & 63;
    const int kb = l >> 4, lr = l & 15;
    const int e = blockIdx.y;
    const int m0 = blockIdx.x << 6;
    const int wm = w >> 2, wn = w & 3;            // 2m x 4n wave grid
    const int sw = w & 3;
    const int sbase = sw << 9;

    const _Float16* w1he = w1h + ((size_t)e << 18);
    const _Float16* w1le = w1l + ((size_t)e << 18);
    const _Float16* w2he = w2h + ((size_t)e << 18);
    const _Float16* w2le = w2l + ((size_t)e << 18);

    // ---- stage 1: acc1 = X @ W1e, weights register-double-buffered ----
    f32x4 acc1[2][8];
    #pragma unroll
    for (int i = 0; i < 2; ++i)
        #pragma unroll
        for (int j = 0; j < 8; ++j) acc1[i][j] = (f32x4){0.f, 0.f, 0.f, 0.f};

    f16x8 pbh[2][8], pbl[2][8];
    #pragma unroll
    for (int j = 0; j < 8; ++j) {              // prefetch k-step 0
        const int n = wn * 128 + j * 16 + lr;
        const size_t gb = ((size_t)(kb << 9) + n) * 8;
        pbh[0][j] = *(const f16x8*)(w1he + gb);
        pbl[0][j] = *(const f16x8*)(w1le + gb);
    }
    {
        const size_t ga = ((size_t)(m0 + l) << 9) + (sw << 3);
        if (tid < 256) gload16(xh + ga, Xh[0] + sbase);
        else           gload16(xl + ga, Xl[0] + sbase);
    }
    #pragma unroll
    for (int kk = 0; kk < 16; ++kk) {
        __syncthreads();                        // X buf[kk&1] ready
        if (kk < 15) {
            const size_t ga = ((size_t)(m0 + l) << 9) + (kk + 1) * 32 + (sw << 3);
            if (tid < 256) gload16(xh + ga, Xh[(kk + 1) & 1] + sbase);
            else           gload16(xl + ga, Xl[(kk + 1) & 1] + sbase);
        }
        f16x8 fah[2], fal[2];
        #pragma unroll
        for (int i = 0; i < 2; ++i) {
            const int off = (kb * 64 + wm * 32 + i * 16 + lr) * 8;
            fah[i] = *(const f16x8*)(Xh[kk & 1] + off);
            fal[i] = *(const f16x8*)(Xl[kk & 1] + off);
        }
        if (kk < 15) {                          // prefetch k-step kk+1 weights
            #pragma unroll
            for (int j = 0; j < 8; ++j) {
                const int n = wn * 128 + j * 16 + lr;
                const size_t gb = ((size_t)(((kk + 1) * 4 + kb) << 9) + n) * 8;
                pbh[(kk + 1) & 1][j] = *(const f16x8*)(w1he + gb);
                pbl[(kk + 1) & 1][j] = *(const f16x8*)(w1le + gb);
            }
        }
        #pragma unroll
        for (int j = 0; j < 8; ++j)
            #pragma unroll
            for (int i = 0; i < 2; ++i) {
                acc1[i][j] = __builtin_amdgcn_mfma_f32_16x16x32_f16(fah[i], pbh[kk & 1][j], acc1[i][j], 0, 0, 0);
                acc1[i][j] = __builtin_amdgcn_mfma_f32_16x16x32_f16(fah[i], pbl[kk & 1][j], acc1[i][j], 0, 0, 0);
                acc1[i][j] = __builtin_amdgcn_mfma_f32_16x16x32_f16(fal[i], pbh[kk & 1][j], acc1[i][j], 0, 0, 0);
            }
    }
    // ---- epilogue 1: gelu+bias+route-scale -> H (split fp16, subtiled) ----
    __syncthreads();
    #pragma unroll
    for (int i = 0; i < 2; ++i)
        #pragma unroll
        for (int j = 0; j < 8; ++j) {
            const int n = wn * 128 + j * 16 + lr;
            const float bv = eb1[(e << 9) + n];
            #pragma unroll
            for (int r = 0; r < 4; ++r) {
                const int ri = wm * 32 + i * 16 + (kb << 2) + r;
                const float v = gelu_f(acc1[i][j][r] + bv) * rw[((size_t)(m0 + ri) << 3) + e];
                _Float16 vh, vl; split2(v, vh, vl);
                const int off = ((n >> 3) * 64 + ri) * 8 + (n & 7);
                Hh[off] = vh; Hl[off] = vl;
            }
        }
    __syncthreads();

    // ---- stage 2: acc2 = H @ W2e, weights register-double-buffered ----
    f32x4 acc2[2][8];
    #pragma unroll
    for (int i = 0; i < 2; ++i)
        #pragma unroll
        for (int j = 0; j < 8; ++j) acc2[i][j] = (f32x4){0.f, 0.f, 0.f, 0.f};

    f16x8 qbh[2][8], qbl[2][8];
    #pragma unroll
    for (int j = 0; j < 8; ++j) {              // prefetch k-step 0
        const int n = wn * 128 + j * 16 + lr;
        const size_t gb = ((size_t)(kb << 9) + n) * 8;
        qbh[0][j] = *(const f16x8*)(w2he + gb);
        qbl[0][j] = *(const f16x8*)(w2le + gb);
    }
    #pragma unroll
    for (int kk = 0; kk < 16; ++kk) {
        f16x8 fah[2], fal[2];
        #pragma unroll
        for (int i = 0; i < 2; ++i) {
            const int off = ((kk * 4 + kb) * 64 + wm * 32 + i * 16 + lr) * 8;
            fah[i] = *(const f16x8*)(Hh + off);
            fal[i] = *(const f16x8*)(Hl + off);
        }
        if (kk < 15) {                          // prefetch k-step kk+1 weights
            #pragma unroll
            for (int j = 0; j < 8; ++j) {
                const int n = wn * 128 + j * 16 + lr;
                const size_t gb = ((size_t)(((kk + 1) * 4 + kb) << 9) + n) * 8;
                qbh[(kk + 1) & 1][j] = *(const f16x8*)(w2he + gb);
                qbl[(kk + 1) & 1][j] = *(const f16x8*)(w2le + gb);
            }
        }
        #pragma unroll
        for (int j = 0; j < 8; ++j)
            #pragma unroll
            for (int i = 0; i < 2; ++i) {
                acc2[i][j] = __builtin_amdgcn_mfma_f32_16x16x32_f16(fah[i], qbh[kk & 1][j], acc2[i][j], 0, 0, 0);
                acc2[i][j] = __builtin_amdgcn_mfma_f32_16x16x32_f16(fah[i], qbl[kk & 1][j], acc2[i][j], 0, 0, 0);
                acc2[i][j] = __builtin_amdgcn_mfma_f32_16x16x32_f16(fal[i], qbh[kk & 1][j], acc2[i][j], 0, 0, 0);
            }
    }
    #pragma unroll
    for (int i = 0; i < 2; ++i)
        #pragma unroll
        for (int j = 0; j < 8; ++j) {
            const int n = wn * 128 + j * 16 + lr;
            #pragma unroll
            for (int r = 0; r < 4; ++r) {
                const int m = m0 + wm * 32 + i * 16 + (kb << 2) + r;
                atomicAdd(&mixed[((size_t)m << 9) + n], acc2[i][j][r]);
            }
        }
}

// ------------------------------------------------------------------
// mixed init: mixed[m][n] = sum_e rw[m][e] * eb2[e][n]. grid = 2048
// ------------------------------------------------------------------
__global__ __launch_bounds__(256)
void init_mixed(const float* __restrict__ rw, const float* __restrict__ eb2,
                float* __restrict__ mixed)
{
    const int idx = blockIdx.x * 256 + threadIdx.x;
    const int m = idx >> 7, n4 = (idx & 127) << 2;
    float rwv[8];
    #pragma unroll
    for (int e = 0; e < 8; ++e) rwv[e] = rw[(m << 3) + e];
    float4 o = {0.f, 0.f, 0.f, 0.f};
    #pragma unroll
    for (int e = 0; e < 8; ++e) {
        const float4 b = *(const float4*)(eb2 + (e << 9) + n4);
        o.x = fmaf(rwv[e], b.x, o.x); o.y = fmaf(rwv[e], b.y, o.y);
        o.z = fmaf(rwv[e], b.z, o.z); o.w = fmaf(rwv[e], b.w, o.w);
    }
    *(float4*)(mixed + ((size_t)m << 9) + n4) = o;
}

// ------------------------------------------------------------------
// Router softmax
// ------------------------------------------------------------------
__global__ __launch_bounds__(256)
void router_kernel(const float* __restrict__ t,
                   const float* __restrict__ rw2,
                   const float* __restrict__ rb2,
                   float* __restrict__ route_w)
{
    __shared__ float s[512 * 9];
    const int tid = threadIdx.x;
    for (int idx = tid; idx < 4096; idx += 256)
        s[(idx >> 3) * 9 + (idx & 7)] = rw2[idx];
    __syncthreads();
    const int lane = tid & 63;
    const int tok = (blockIdx.x << 2) + (tid >> 6);
    const float* tp = t + ((size_t)tok << 9);
    float acc[8] = {};
    #pragma unroll
    for (int kq = 0; kq < 8; ++kq) {
        const int k = (kq << 6) + lane;
        const float tv = tp[k];
        #pragma unroll
        for (int e = 0; e < 8; ++e)
            acc[e] = fmaf(tv, s[k * 9 + e], acc[e]);
    }
    #pragma unroll
    for (int e = 0; e < 8; ++e)
        #pragma unroll
        for (int off = 32; off; off >>= 1)
            acc[e] += __shfl_xor(acc[e], off, 64);
    float mx = -1e30f;
    #pragma unroll
    for (int e = 0; e < 8; ++e) { acc[e] += rb2[e]; mx = fmaxf(mx, acc[e]); }
    float sum = 0.f;
    #pragma unroll
    for (int e = 0; e < 8; ++e) { acc[e] = expf(acc[e] - mx); sum += acc[e]; }
    const float inv = 1.0f / sum;
    if (lane == 0) {
        #pragma unroll
        for (int e = 0; e < 8; ++e) route_w[(tok << 3) + e] = acc[e] * inv;
    }
}

// ------------------------------------------------------------------
// Final: top-2 + masked softmax + blend + LayerNorm, one block/token.
// ------------------------------------------------------------------
__global__ __launch_bounds__(256)
void final_kernel(const float* __restrict__ mixedb,
                  const float* __restrict__ mlog,
                  const float* __restrict__ sb2,
                  const float* __restrict__ g,
                  const float* __restrict__ bta,
                  float* __restrict__ out)
{
    const int tok = blockIdx.x, tid = threadIdx.x;
    float v[4];
    #pragma unroll
    for (int m = 0; m < 4; ++m) v[m] = mlog[(tok << 2) + m] + sb2[0];
    int i1 = 0;
    #pragma unroll
    for (int m = 1; m < 4; ++m) if (v[m] > v[i1]) i1 = m;
    int i2 = (i1 == 0) ? 1 : 0;
    for (int m = i2 + 1; m < 4; ++m) if (m != i1 && v[m] > v[i2]) i2 = m;
    const float e2 = expf(v[i2] - v[i1]);
    const float winv = 1.0f / (1.0f + e2);
    const float w1 = winv, w2 = e2 * winv;
    const float* p1 = mixedb + (((size_t)i1 * TOK + tok) << 9);
    const float* p2 = mixedb + (((size_t)i2 * TOK + tok) << 9);
    const int h0 = tid, h1 = tid + 256;
    const float c0 = w1 * p1[h0] + w2 * p2[h0];
    const float c1 = w1 * p1[h1] + w2 * p2[h1];
    float s = c0 + c1, sq = c0 * c0 + c1 * c1;
    #pragma unroll
    for (int off = 32; off; off >>= 1) {
        s += __shfl_xor(s, off, 64);
        sq += __shfl_xor(sq, off, 64);
    }
    __shared__ float red[8];
    const int wv = tid >> 6, ln = tid & 63;
    if (ln == 0) { red[wv] = s; red[4 + wv] = sq; }
    __syncthreads();
    s = red[0] + red[1] + red[2] + red[3];
    sq = red[4] + red[5] + red[6] + red[7];
    const float mu = s * (1.0f / 512.0f);
    const float var = sq * (1.0f / 512.0f) - mu * mu;
    const float r = 1.0f / sqrtf(var + 1e-5f);
    out[((size_t)tok << 9) + h0] = (c0 - mu) * r * g[h0] + bta[h0];
    out[((size_t)tok << 9) + h1] = (c1 - mu) * r * g[h1] + bta[h1];
}

extern "C" void kernel_launch(void* const* d_in, const int* in_sizes, int n_in,
                              void* d_out, int out_size, void* d_ws, size_t ws_size,
                              hipStream_t stream)
{
    (void)in_sizes; (void)n_in; (void)out_size; (void)ws_size;
    const float* ew1  = (const float*)d_in[12];
    const float* eb1  = (const float*)d_in[13];
    const float* ew2  = (const float*)d_in[14];
    const float* eb2  = (const float*)d_in[15];
    const float* rw1  = (const float*)d_in[16];
    const float* rb1  = (const float*)d_in[17];
    const float* rw2  = (const float*)d_in[18];
    const float* rb2  = (const float*)d_in[19];
    const float* sw1  = (const float*)d_in[20];
    const float* sb1  = (const float*)d_in[21];
    const float* sw2  = (const float*)d_in[22];
    const float* sb2  = (const float*)d_in[23];
    const float* ln_g = (const float*)d_in[24];
    const float* ln_b = (const float*)d_in[25];
    const int KD[4] = {1024, 64, 768, 512};

    // ---- workspace layout ----
    char* p = (char*)d_ws;
    auto alloc = [&](size_t bytes) {
        void* r = (void*)p;
        p += (bytes + 255) & ~(size_t)255;
        return r;
    };
    float*     mixedb  = (float*)alloc((size_t)4 * TOK * HD * 4);
    float*     scratch = (float*)alloc((size_t)TOK * HD * 4);   // t
    float*     route_w = (float*)alloc((size_t)TOK * 8 * 4);
    float*     mlog    = (float*)alloc((size_t)TOK * 4 * 4);
    _Float16*  xh      = (_Float16*)alloc((size_t)TOK * HD * 2);
    _Float16*  xl      = (_Float16*)alloc((size_t)TOK * HD * 2);
    _Float16*  mxh     = (_Float16*)alloc((size_t)TOK * HD * 2);
    _Float16*  mxl     = (_Float16*)alloc((size_t)TOK * HD * 2);
    _Float16*  fh      = (_Float16*)alloc((size_t)TOK * 1024 * 2);
    _Float16*  fl      = (_Float16*)alloc((size_t)TOK * 1024 * 2);
    _Float16*  pwh     = (_Float16*)alloc((size_t)1024 * HD * 2);
    _Float16*  pwl     = (_Float16*)alloc((size_t)1024 * HD * 2);
    _Float16*  rw1h    = (_Float16*)alloc((size_t)HD * HD * 2);
    _Float16*  rw1l    = (_Float16*)alloc((size_t)HD * HD * 2);
    _Float16*  sw1h    = (_Float16*)alloc((size_t)HD * HD * 2);
    _Float16*  sw1l    = (_Float16*)alloc((size_t)HD * HD * 2);
    _Float16*  w1h     = (_Float16*)alloc((size_t)8 * HD * HD * 2);
    _Float16*  w1l     = (_Float16*)alloc((size_t)8 * HD * HD * 2);
    _Float16*  w2h     = (_Float16*)alloc((size_t)8 * HD * HD * 2);
    _Float16*  w2l     = (_Float16*)alloc((size_t)8 * HD * HD * 2);

    // mlog accumulated via atomics -> zero it (ws is re-poisoned every call)
    hipMemsetAsync(mlog, 0, (size_t)TOK * 4 * sizeof(float), stream);

    // ---- weight prep (frag layout splits) ----
    split_w_kernel<<<dim3(1024), 256, 0, stream>>>(ew1, w1h, w1l);
    split_w_kernel<<<dim3(1024), 256, 0, stream>>>(ew2, w2h, w2l);
    split_w_kernel<<<dim3(128), 256, 0, stream>>>(rw1, rw1h, rw1l);
    split_w_kernel<<<dim3(128), 256, 0, stream>>>(sw1, sw1h, sw1l);

    for (int mod = 0; mod < 4; ++mod) {
        const float* feat = (const float*)d_in[mod * 3 + 0];
        const float* pw   = (const float*)d_in[mod * 3 + 1];
        const float* pb   = (const float*)d_in[mod * 3 + 2];
        float* mixm = mixedb + (size_t)mod * TOK * HD;
        const int K = KD[mod];

        // splits for this modality
        split_x_kernel<<<dim3(TOK * K / 2048), 256, 0, stream>>>(feat, fh, fl);
        split_w_kernel<<<dim3(K / 4), 256, 0, stream>>>(pw, pwh, pwl);
        // x = feat @ pw + pb  -> xh/xl
        gemm_hh<0, 1><<<dim3(4, 64), 256, 0, stream>>>(
            fh, fl, pwh, pwl, pb, K, nullptr, xh, xl, nullptr, nullptr);
        // t = gelu(x @ rw1 + rb1)
        gemm_hh<1, 0><<<dim3(4, 64), 256, 0, stream>>>(
            xh, xl, rw1h, rw1l, rb1, HD, scratch, nullptr, nullptr, nullptr, nullptr);
        // route_w = softmax(t @ rw2 + rb2)
        router_kernel<<<dim3(TOK / 4), 256, 0, stream>>>(scratch, rw2, rb2, route_w);
        // mixed = sum_e rw*eb2, then fused experts accumulate
        init_mixed<<<dim3(TOK * HD / 4 / 256), 256, 0, stream>>>(route_w, eb2, mixm);
        fused_expert5<<<dim3(64, 8), 512, 0, stream>>>(
            xh, xl, w1h, w1l, w2h, w2l, eb1, route_w, mixm);
        // u = gelu(mixed @ sw1 + sb1); score fused into epilogue -> mlog
        split_x_kernel<<<dim3(TOK * HD / 2048), 256, 0, stream>>>(mixm, mxh, mxl);
        gemm_hh<1, 2><<<dim3(4, 64), 256, 0, stream>>>(
            mxh, mxl, sw1h, sw1l, sb1, HD, nullptr, nullptr, nullptr,
            sw2, mlog + mod);
    }
    final_kernel<<<dim3(TOK), 256, 0, stream>>>(mixedb, mlog, sb2, ln_g, ln_b, (float*)d_out);
}

// Round 9
// 1298.951 us; speedup vs baseline: 1.0958x; 1.0482x over previous
//
#include <hip/hip_runtime.h>
#include <math.h>

#define TOK 4096
#define HD 512

typedef _Float16 f16x8 __attribute__((ext_vector_type(8)));
typedef float f32x4 __attribute__((ext_vector_type(4)));

__device__ __forceinline__ float gelu_f(float x) {
    return 0.5f * x * (1.0f + erff(x * 0.70710678118654752f));
}

__device__ __forceinline__ void gload16(const void* g, void* l) {
    __builtin_amdgcn_global_load_lds((const __attribute__((address_space(1))) void*)g,
                                     (__attribute__((address_space(3))) void*)l, 16, 0, 0);
}

__device__ __forceinline__ void split2(float v, _Float16& h, _Float16& l) {
    h = (_Float16)v;
    l = (_Float16)(v - (float)h);
}

// ------------------------------------------------------------------
// fp32 -> (hi,lo) fp16, 8 elems/thread. grid = numel/2048
// ------------------------------------------------------------------
__global__ __launch_bounds__(256)
void split_x_kernel(const float* __restrict__ in, _Float16* __restrict__ hi,
                    _Float16* __restrict__ lo)
{
    const size_t idx = (size_t)blockIdx.x * 256 + threadIdx.x;
    const float4 v0 = *(const float4*)(in + idx * 8);
    const float4 v1 = *(const float4*)(in + idx * 8 + 4);
    float vv[8] = {v0.x, v0.y, v0.z, v0.w, v1.x, v1.y, v1.z, v1.w};
    f16x8 h, l;
    #pragma unroll
    for (int j = 0; j < 8; ++j) {
        _Float16 a, b; split2(vv[j], a, b);
        h[j] = a; l[j] = b;
    }
    *(f16x8*)(hi + idx * 8) = h;
    *(f16x8*)(lo + idx * 8) = l;
}

// ------------------------------------------------------------------
// Weight prep: [Ktot][512] fp32 row-major -> frag layout [Ktot/8][512][8]
// hi/lo fp16 (8 = k-minor). grid = Ktot*512/2048 blocks.
// ------------------------------------------------------------------
__global__ __launch_bounds__(256)
void split_w_kernel(const float* __restrict__ w, _Float16* __restrict__ hi,
                    _Float16* __restrict__ lo)
{
    const int idx = blockIdx.x * 256 + threadIdx.x;
    const int kbG = idx >> 9, n = idx & 511;
    const float* src = w + (((size_t)kbG * 8) << 9) + n;
    f16x8 h, l;
    #pragma unroll
    for (int j = 0; j < 8; ++j) {
        const float v = src[(size_t)j << 9];
        _Float16 a, b; split2(v, a, b);
        h[j] = a; l[j] = b;
    }
    *(f16x8*)(hi + (size_t)idx * 8) = h;
    *(f16x8*)(lo + (size_t)idx * 8) = l;
}

// ------------------------------------------------------------------
// Split-fp16 MFMA GEMM: out[M=4096][512] = act(A[M][K] @ Bfrag + bias)
// OSPL: 0 = fp32 out; 1 = split fp16 out; 2 = score mode (atomicAdd
//       sum(gelu(v)*sw2[n]) into mlog4[m*4]).
// ------------------------------------------------------------------
template<int ACT, int OSPL>
__global__ __launch_bounds__(256, 2)
void gemm_hh(const _Float16* __restrict__ ah, const _Float16* __restrict__ al,
             const _Float16* __restrict__ bh, const _Float16* __restrict__ bl,
             const float* __restrict__ bias, int K,
             float* __restrict__ outF,
             _Float16* __restrict__ oh, _Float16* __restrict__ ol,
             const float* __restrict__ sw2, float* __restrict__ mlog4)
{
    __shared__ _Float16 Ah[2][2048], Al[2][2048];
    const int tid = threadIdx.x;
    const int l = tid & 63, w = tid >> 6;
    const int kb = l >> 4, lr = l & 15;
    const int m0 = blockIdx.y << 6;
    const int wn0 = (blockIdx.x << 7) + (w << 5);
    const int scr = tid & 63, sckb = tid >> 6;
    const int sbase = (tid & 192) * 8;

    f32x4 acc[4][2];
    #pragma unroll
    for (int i = 0; i < 4; ++i)
        #pragma unroll
        for (int j = 0; j < 2; ++j) acc[i][j] = (f32x4){0.f, 0.f, 0.f, 0.f};

    {
        const size_t ga = (size_t)(m0 + scr) * K + sckb * 8;
        gload16(ah + ga, Ah[0] + sbase);
        gload16(al + ga, Al[0] + sbase);
    }
    int cur = 0;
    for (int k0 = 0; k0 < K; k0 += 32) {
        __syncthreads();
        if (k0 + 32 < K) {
            const size_t ga = (size_t)(m0 + scr) * K + k0 + 32 + sckb * 8;
            gload16(ah + ga, Ah[cur ^ 1] + sbase);
            gload16(al + ga, Al[cur ^ 1] + sbase);
        }
        f16x8 fah[4], fal[4];
        #pragma unroll
        for (int i = 0; i < 4; ++i) {
            const int off = (kb * 64 + i * 16 + lr) * 8;
            fah[i] = *(const f16x8*)(Ah[cur] + off);
            fal[i] = *(const f16x8*)(Al[cur] + off);
        }
        #pragma unroll
        for (int j = 0; j < 2; ++j) {
            const size_t gb = ((size_t)(((k0 >> 3) + kb) << 9) + wn0 + j * 16 + lr) * 8;
            const f16x8 fbh = *(const f16x8*)(bh + gb);
            const f16x8 fbl = *(const f16x8*)(bl + gb);
            #pragma unroll
            for (int i = 0; i < 4; ++i) {
                acc[i][j] = __builtin_amdgcn_mfma_f32_16x16x32_f16(fah[i], fbh, acc[i][j], 0, 0, 0);
                acc[i][j] = __builtin_amdgcn_mfma_f32_16x16x32_f16(fah[i], fbl, acc[i][j], 0, 0, 0);
                acc[i][j] = __builtin_amdgcn_mfma_f32_16x16x32_f16(fal[i], fbh, acc[i][j], 0, 0, 0);
            }
        }
        cur ^= 1;
    }
    #pragma unroll
    for (int i = 0; i < 4; ++i) {
        float sacc[4] = {0.f, 0.f, 0.f, 0.f};
        #pragma unroll
        for (int j = 0; j < 2; ++j) {
            const int n = wn0 + j * 16 + lr;
            const float bv = bias[n];
            const float swv = (OSPL == 2) ? sw2[n] : 0.f;
            #pragma unroll
            for (int r = 0; r < 4; ++r) {
                const int m = m0 + i * 16 + (kb << 2) + r;
                float v = acc[i][j][r] + bv;
                if (ACT) v = gelu_f(v);
                if (OSPL == 2) {
                    sacc[r] = fmaf(v, swv, sacc[r]);
                } else if (OSPL == 1) {
                    _Float16 vh, vl; split2(v, vh, vl);
                    oh[((size_t)m << 9) + n] = vh;
                    ol[((size_t)m << 9) + n] = vl;
                } else {
                    outF[((size_t)m << 9) + n] = v;
                }
            }
        }
        if (OSPL == 2) {
            #pragma unroll
            for (int r = 0; r < 4; ++r) {
                float s = sacc[r];
                s += __shfl_xor(s, 1, 64);
                s += __shfl_xor(s, 2, 64);
                s += __shfl_xor(s, 4, 64);
                s += __shfl_xor(s, 8, 64);
                if (lr == 0) {
                    const int m = m0 + i * 16 + (kb << 2) + r;
                    atomicAdd(&mlog4[m << 2], s);
                }
            }
        }
    }
}

// ------------------------------------------------------------------
// Fused expert v6: barrier-free K-loops.
// grid = (64, 8), y = expert (R6/R8-proven L2 behavior), 512 threads.
// X is read DIRECTLY global->VGPR (8 MB, L2-hot, no LDS staging) so the
// K-loops have NO __syncthreads -- waves run decoupled, and explicit
// 2-deep register double-buffers (compile-time indexed) let each wave's
// next-iter weight/X loads fly under its current-iter 48 MFMAs.
// Stage 1: H = gelu(X@W1e + b1e)*rw -> LDS split-fp16 [64 kgrp][64 row][8]
// ONE barrier (H write -> H read). Stage 2: mixed += H @ W2e (atomicAdd).
// LDS 128 KB -> 1 block/CU, 8 waves (2/SIMD); launch_bounds(512,2)
// allows ~240 VGPR for the pipeline buffers.
// ------------------------------------------------------------------
__global__ __launch_bounds__(512, 2)
void fused_expert6(const _Float16* __restrict__ xh, const _Float16* __restrict__ xl,
                   const _Float16* __restrict__ w1h, const _Float16* __restrict__ w1l,
                   const _Float16* __restrict__ w2h, const _Float16* __restrict__ w2l,
                   const float* __restrict__ eb1, const float* __restrict__ rw,
                   float* __restrict__ mixed)
{
    __shared__ _Float16 Hh[32768], Hl[32768];     // [64 kgrp][64 row][8]
    const int tid = threadIdx.x;
    const int w = tid >> 6, l = tid & 63;
    const int kb = l >> 4, lr = l & 15;
    const int e = blockIdx.y;
    const int m0 = blockIdx.x << 6;
    const int wm = w >> 2, wn = w & 3;            // 2m x 4n wave grid

    const _Float16* w1he = w1h + ((size_t)e << 18);
    const _Float16* w1le = w1l + ((size_t)e << 18);
    const _Float16* w2he = w2h + ((size_t)e << 18);
    const _Float16* w2le = w2l + ((size_t)e << 18);

    // ---- stage 1: acc1 = X @ W1e  (barrier-free, dbuf'd) ----
    f32x4 acc1[2][8];
    #pragma unroll
    for (int i = 0; i < 2; ++i)
        #pragma unroll
        for (int j = 0; j < 8; ++j) acc1[i][j] = (f32x4){0.f, 0.f, 0.f, 0.f};

    f16x8 pbh[2][8], pbl[2][8];   // weight frag dbuf
    f16x8 fxh[2][2], fxl[2][2];   // X frag dbuf
    #pragma unroll
    for (int j = 0; j < 8; ++j) {
        const int n = wn * 128 + j * 16 + lr;
        const size_t gb = ((size_t)(kb << 9) + n) * 8;
        pbh[0][j] = *(const f16x8*)(w1he + gb);
        pbl[0][j] = *(const f16x8*)(w1le + gb);
    }
    #pragma unroll
    for (int i = 0; i < 2; ++i) {
        const size_t ga = ((size_t)(m0 + wm * 32 + i * 16 + lr) << 9) + kb * 8;
        fxh[0][i] = *(const f16x8*)(xh + ga);
        fxl[0][i] = *(const f16x8*)(xl + ga);
    }
    #pragma unroll
    for (int kk = 0; kk < 16; ++kk) {
        const int cur = kk & 1, nxt = cur ^ 1;
        if (kk < 15) {
            #pragma unroll
            for (int j = 0; j < 8; ++j) {
                const int n = wn * 128 + j * 16 + lr;
                const size_t gb = ((size_t)(((kk + 1) * 4 + kb) << 9) + n) * 8;
                pbh[nxt][j] = *(const f16x8*)(w1he + gb);
                pbl[nxt][j] = *(const f16x8*)(w1le + gb);
            }
            #pragma unroll
            for (int i = 0; i < 2; ++i) {
                const size_t ga = ((size_t)(m0 + wm * 32 + i * 16 + lr) << 9)
                                  + (kk + 1) * 32 + kb * 8;
                fxh[nxt][i] = *(const f16x8*)(xh + ga);
                fxl[nxt][i] = *(const f16x8*)(xl + ga);
            }
        }
        #pragma unroll
        for (int j = 0; j < 8; ++j)
            #pragma unroll
            for (int i = 0; i < 2; ++i) {
                acc1[i][j] = __builtin_amdgcn_mfma_f32_16x16x32_f16(fxh[cur][i], pbh[cur][j], acc1[i][j], 0, 0, 0);
                acc1[i][j] = __builtin_amdgcn_mfma_f32_16x16x32_f16(fxh[cur][i], pbl[cur][j], acc1[i][j], 0, 0, 0);
                acc1[i][j] = __builtin_amdgcn_mfma_f32_16x16x32_f16(fxl[cur][i], pbh[cur][j], acc1[i][j], 0, 0, 0);
            }
    }
    // ---- epilogue 1: gelu+bias+route-scale -> H (split fp16, subtiled) ----
    #pragma unroll
    for (int i = 0; i < 2; ++i)
        #pragma unroll
        for (int j = 0; j < 8; ++j) {
            const int n = wn * 128 + j * 16 + lr;
            const float bv = eb1[(e << 9) + n];
            #pragma unroll
            for (int r = 0; r < 4; ++r) {
                const int ri = wm * 32 + i * 16 + (kb << 2) + r;
                const float v = gelu_f(acc1[i][j][r] + bv) * rw[((size_t)(m0 + ri) << 3) + e];
                _Float16 vh, vl; split2(v, vh, vl);
                const int off = ((n >> 3) * 64 + ri) * 8 + (n & 7);
                Hh[off] = vh; Hl[off] = vl;
            }
        }
    __syncthreads();   // the ONLY barrier: H fully written before reads

    // ---- stage 2: acc2 = H @ W2e  (barrier-free, dbuf'd weights) ----
    f32x4 acc2[2][8];
    #pragma unroll
    for (int i = 0; i < 2; ++i)
        #pragma unroll
        for (int j = 0; j < 8; ++j) acc2[i][j] = (f32x4){0.f, 0.f, 0.f, 0.f};

    f16x8 qbh[2][8], qbl[2][8];
    #pragma unroll
    for (int j = 0; j < 8; ++j) {
        const int n = wn * 128 + j * 16 + lr;
        const size_t gb = ((size_t)(kb << 9) + n) * 8;
        qbh[0][j] = *(const f16x8*)(w2he + gb);
        qbl[0][j] = *(const f16x8*)(w2le + gb);
    }
    #pragma unroll
    for (int kk = 0; kk < 16; ++kk) {
        const int cur = kk & 1, nxt = cur ^ 1;
        if (kk < 15) {
            #pragma unroll
            for (int j = 0; j < 8; ++j) {
                const int n = wn * 128 + j * 16 + lr;
                const size_t gb = ((size_t)(((kk + 1) * 4 + kb) << 9) + n) * 8;
                qbh[nxt][j] = *(const f16x8*)(w2he + gb);
                qbl[nxt][j] = *(const f16x8*)(w2le + gb);
            }
        }
        f16x8 fah[2], fal[2];
        #pragma unroll
        for (int i = 0; i < 2; ++i) {
            const int off = ((kk * 4 + kb) * 64 + wm * 32 + i * 16 + lr) * 8;
            fah[i] = *(const f16x8*)(Hh + off);
            fal[i] = *(const f16x8*)(Hl + off);
        }
        #pragma unroll
        for (int j = 0; j < 8; ++j)
            #pragma unroll
            for (int i = 0; i < 2; ++i) {
                acc2[i][j] = __builtin_amdgcn_mfma_f32_16x16x32_f16(fah[i], qbh[cur][j], acc2[i][j], 0, 0, 0);
                acc2[i][j] = __builtin_amdgcn_mfma_f32_16x16x32_f16(fah[i], qbl[cur][j], acc2[i][j], 0, 0, 0);
                acc2[i][j] = __builtin_amdgcn_mfma_f32_16x16x32_f16(fal[i], qbh[cur][j], acc2[i][j], 0, 0, 0);
            }
    }
    #pragma unroll
    for (int i = 0; i < 2; ++i)
        #pragma unroll
        for (int j = 0; j < 8; ++j) {
            const int n = wn * 128 + j * 16 + lr;
            #pragma unroll
            for (int r = 0; r < 4; ++r) {
                const int m = m0 + wm * 32 + i * 16 + (kb << 2) + r;
                atomicAdd(&mixed[((size_t)m << 9) + n], acc2[i][j][r]);
            }
        }
}

// ------------------------------------------------------------------
// mixed init: mixed[m][n] = sum_e rw[m][e] * eb2[e][n]. grid = 2048
// ------------------------------------------------------------------
__global__ __launch_bounds__(256)
void init_mixed(const float* __restrict__ rw, const float* __restrict__ eb2,
                float* __restrict__ mixed)
{
    const int idx = blockIdx.x * 256 + threadIdx.x;
    const int m = idx >> 7, n4 = (idx & 127) << 2;
    float rwv[8];
    #pragma unroll
    for (int e = 0; e < 8; ++e) rwv[e] = rw[(m << 3) + e];
    float4 o = {0.f, 0.f, 0.f, 0.f};
    #pragma unroll
    for (int e = 0; e < 8; ++e) {
        const float4 b = *(const float4*)(eb2 + (e << 9) + n4);
        o.x = fmaf(rwv[e], b.x, o.x); o.y = fmaf(rwv[e], b.y, o.y);
        o.z = fmaf(rwv[e], b.z, o.z); o.w = fmaf(rwv[e], b.w, o.w);
    }
    *(float4*)(mixed + ((size_t)m << 9) + n4) = o;
}

// ------------------------------------------------------------------
// Router softmax
// ------------------------------------------------------------------
__global__ __launch_bounds__(256)
void router_kernel(const float* __restrict__ t,
                   const float* __restrict__ rw2,
                   const float* __restrict__ rb2,
                   float* __restrict__ route_w)
{
    __shared__ float s[512 * 9];
    const int tid = threadIdx.x;
    for (int idx = tid; idx < 4096; idx += 256)
        s[(idx >> 3) * 9 + (idx & 7)] = rw2[idx];
    __syncthreads();
    const int lane = tid & 63;
    const int tok = (blockIdx.x << 2) + (tid >> 6);
    const float* tp = t + ((size_t)tok << 9);
    float acc[8] = {};
    #pragma unroll
    for (int kq = 0; kq < 8; ++kq) {
        const int k = (kq << 6) + lane;
        const float tv = tp[k];
        #pragma unroll
        for (int e = 0; e < 8; ++e)
            acc[e] = fmaf(tv, s[k * 9 + e], acc[e]);
    }
    #pragma unroll
    for (int e = 0; e < 8; ++e)
        #pragma unroll
        for (int off = 32; off; off >>= 1)
            acc[e] += __shfl_xor(acc[e], off, 64);
    float mx = -1e30f;
    #pragma unroll
    for (int e = 0; e < 8; ++e) { acc[e] += rb2[e]; mx = fmaxf(mx, acc[e]); }
    float sum = 0.f;
    #pragma unroll
    for (int e = 0; e < 8; ++e) { acc[e] = expf(acc[e] - mx); sum += acc[e]; }
    const float inv = 1.0f / sum;
    if (lane == 0) {
        #pragma unroll
        for (int e = 0; e < 8; ++e) route_w[(tok << 3) + e] = acc[e] * inv;
    }
}

// ------------------------------------------------------------------
// Final: top-2 + masked softmax + blend + LayerNorm, one block/token.
// ------------------------------------------------------------------
__global__ __launch_bounds__(256)
void final_kernel(const float* __restrict__ mixedb,
                  const float* __restrict__ mlog,
                  const float* __restrict__ sb2,
                  const float* __restrict__ g,
                  const float* __restrict__ bta,
                  float* __restrict__ out)
{
    const int tok = blockIdx.x, tid = threadIdx.x;
    float v[4];
    #pragma unroll
    for (int m = 0; m < 4; ++m) v[m] = mlog[(tok << 2) + m] + sb2[0];
    int i1 = 0;
    #pragma unroll
    for (int m = 1; m < 4; ++m) if (v[m] > v[i1]) i1 = m;
    int i2 = (i1 == 0) ? 1 : 0;
    for (int m = i2 + 1; m < 4; ++m) if (m != i1 && v[m] > v[i2]) i2 = m;
    const float e2 = expf(v[i2] - v[i1]);
    const float winv = 1.0f / (1.0f + e2);
    const float w1 = winv, w2 = e2 * winv;
    const float* p1 = mixedb + (((size_t)i1 * TOK + tok) << 9);
    const float* p2 = mixedb + (((size_t)i2 * TOK + tok) << 9);
    const int h0 = tid, h1 = tid + 256;
    const float c0 = w1 * p1[h0] + w2 * p2[h0];
    const float c1 = w1 * p1[h1] + w2 * p2[h1];
    float s = c0 + c1, sq = c0 * c0 + c1 * c1;
    #pragma unroll
    for (int off = 32; off; off >>= 1) {
        s += __shfl_xor(s, off, 64);
        sq += __shfl_xor(sq, off, 64);
    }
    __shared__ float red[8];
    const int wv = tid >> 6, ln = tid & 63;
    if (ln == 0) { red[wv] = s; red[4 + wv] = sq; }
    __syncthreads();
    s = red[0] + red[1] + red[2] + red[3];
    sq = red[4] + red[5] + red[6] + red[7];
    const float mu = s * (1.0f / 512.0f);
    const float var = sq * (1.0f / 512.0f) - mu * mu;
    const float r = 1.0f / sqrtf(var + 1e-5f);
    out[((size_t)tok << 9) + h0] = (c0 - mu) * r * g[h0] + bta[h0];
    out[((size_t)tok << 9) + h1] = (c1 - mu) * r * g[h1] + bta[h1];
}

extern "C" void kernel_launch(void* const* d_in, const int* in_sizes, int n_in,
                              void* d_out, int out_size, void* d_ws, size_t ws_size,
                              hipStream_t stream)
{
    (void)in_sizes; (void)n_in; (void)out_size; (void)ws_size;
    const float* ew1  = (const float*)d_in[12];
    const float* eb1  = (const float*)d_in[13];
    const float* ew2  = (const float*)d_in[14];
    const float* eb2  = (const float*)d_in[15];
    const float* rw1  = (const float*)d_in[16];
    const float* rb1  = (const float*)d_in[17];
    const float* rw2  = (const float*)d_in[18];
    const float* rb2  = (const float*)d_in[19];
    const float* sw1  = (const float*)d_in[20];
    const float* sb1  = (const float*)d_in[21];
    const float* sw2  = (const float*)d_in[22];
    const float* sb2  = (const float*)d_in[23];
    const float* ln_g = (const float*)d_in[24];
    const float* ln_b = (const float*)d_in[25];
    const int KD[4] = {1024, 64, 768, 512};

    // ---- workspace layout ----
    char* p = (char*)d_ws;
    auto alloc = [&](size_t bytes) {
        void* r = (void*)p;
        p += (bytes + 255) & ~(size_t)255;
        return r;
    };
    float*     mixedb  = (float*)alloc((size_t)4 * TOK * HD * 4);
    float*     scratch = (float*)alloc((size_t)TOK * HD * 4);   // t
    float*     route_w = (float*)alloc((size_t)TOK * 8 * 4);
    float*     mlog    = (float*)alloc((size_t)TOK * 4 * 4);
    _Float16*  xh      = (_Float16*)alloc((size_t)TOK * HD * 2);
    _Float16*  xl      = (_Float16*)alloc((size_t)TOK * HD * 2);
    _Float16*  mxh     = (_Float16*)alloc((size_t)TOK * HD * 2);
    _Float16*  mxl     = (_Float16*)alloc((size_t)TOK * HD * 2);
    _Float16*  fh      = (_Float16*)alloc((size_t)TOK * 1024 * 2);
    _Float16*  fl      = (_Float16*)alloc((size_t)TOK * 1024 * 2);
    _Float16*  pwh     = (_Float16*)alloc((size_t)1024 * HD * 2);
    _Float16*  pwl     = (_Float16*)alloc((size_t)1024 * HD * 2);
    _Float16*  rw1h    = (_Float16*)alloc((size_t)HD * HD * 2);
    _Float16*  rw1l    = (_Float16*)alloc((size_t)HD * HD * 2);
    _Float16*  sw1h    = (_Float16*)alloc((size_t)HD * HD * 2);
    _Float16*  sw1l    = (_Float16*)alloc((size_t)HD * HD * 2);
    _Float16*  w1h     = (_Float16*)alloc((size_t)8 * HD * HD * 2);
    _Float16*  w1l     = (_Float16*)alloc((size_t)8 * HD * HD * 2);
    _Float16*  w2h     = (_Float16*)alloc((size_t)8 * HD * HD * 2);
    _Float16*  w2l     = (_Float16*)alloc((size_t)8 * HD * HD * 2);

    // mlog accumulated via atomics -> zero it (ws is re-poisoned every call)
    hipMemsetAsync(mlog, 0, (size_t)TOK * 4 * sizeof(float), stream);

    // ---- weight prep (frag layout splits) ----
    split_w_kernel<<<dim3(1024), 256, 0, stream>>>(ew1, w1h, w1l);
    split_w_kernel<<<dim3(1024), 256, 0, stream>>>(ew2, w2h, w2l);
    split_w_kernel<<<dim3(128), 256, 0, stream>>>(rw1, rw1h, rw1l);
    split_w_kernel<<<dim3(128), 256, 0, stream>>>(sw1, sw1h, sw1l);

    for (int mod = 0; mod < 4; ++mod) {
        const float* feat = (const float*)d_in[mod * 3 + 0];
        const float* pw   = (const float*)d_in[mod * 3 + 1];
        const float* pb   = (const float*)d_in[mod * 3 + 2];
        float* mixm = mixedb + (size_t)mod * TOK * HD;
        const int K = KD[mod];

        // splits for this modality
        split_x_kernel<<<dim3(TOK * K / 2048), 256, 0, stream>>>(feat, fh, fl);
        split_w_kernel<<<dim3(K / 4), 256, 0, stream>>>(pw, pwh, pwl);
        // x = feat @ pw + pb  -> xh/xl
        gemm_hh<0, 1><<<dim3(4, 64), 256, 0, stream>>>(
            fh, fl, pwh, pwl, pb, K, nullptr, xh, xl, nullptr, nullptr);
        // t = gelu(x @ rw1 + rb1)
        gemm_hh<1, 0><<<dim3(4, 64), 256, 0, stream>>>(
            xh, xl, rw1h, rw1l, rb1, HD, scratch, nullptr, nullptr, nullptr, nullptr);
        // route_w = softmax(t @ rw2 + rb2)
        router_kernel<<<dim3(TOK / 4), 256, 0, stream>>>(scratch, rw2, rb2, route_w);
        // mixed = sum_e rw*eb2, then fused experts accumulate
        init_mixed<<<dim3(TOK * HD / 4 / 256), 256, 0, stream>>>(route_w, eb2, mixm);
        fused_expert6<<<dim3(64, 8), 512, 0, stream>>>(
            xh, xl, w1h, w1l, w2h, w2l, eb1, route_w, mixm);
        // u = gelu(mixed @ sw1 + sb1); score fused into epilogue -> mlog
        split_x_kernel<<<dim3(TOK * HD / 2048), 256, 0, stream>>>(mixm, mxh, mxl);
        gemm_hh<1, 2><<<dim3(4, 64), 256, 0, stream>>>(
            mxh, mxl, sw1h, sw1l, sb1, HD, nullptr, nullptr, nullptr,
            sw2, mlog + mod);
    }
    final_kernel<<<dim3(TOK), 256, 0, stream>>>(mixedb, mlog, sb2, ln_g, ln_b, (float*)d_out);
}

// Round 10
// 1271.038 us; speedup vs baseline: 1.1199x; 1.0220x over previous
//
#include <hip/hip_runtime.h>
#include <math.h>

#define TOK 4096
#define HD 512

typedef _Float16 f16x8 __attribute__((ext_vector_type(8)));
typedef float f32x4 __attribute__((ext_vector_type(4)));

__device__ __forceinline__ float gelu_f(float x) {
    return 0.5f * x * (1.0f + erff(x * 0.70710678118654752f));
}

__device__ __forceinline__ void gload16(const void* g, void* l) {
    __builtin_amdgcn_global_load_lds((const __attribute__((address_space(1))) void*)g,
                                     (__attribute__((address_space(3))) void*)l, 16, 0, 0);
}

__device__ __forceinline__ void split2(float v, _Float16& h, _Float16& l) {
    h = (_Float16)v;
    l = (_Float16)(v - (float)h);
}

// ------------------------------------------------------------------
// Weight prep: [Ktot][512] fp32 row-major -> frag layout [Ktot/8][512][8]
// hi/lo fp16 (8 = k-minor). grid = Ktot*512/2048 blocks.
// ------------------------------------------------------------------
__global__ __launch_bounds__(256)
void split_w_kernel(const float* __restrict__ w, _Float16* __restrict__ hi,
                    _Float16* __restrict__ lo)
{
    const int idx = blockIdx.x * 256 + threadIdx.x;
    const int kbG = idx >> 9, n = idx & 511;
    const float* src = w + (((size_t)kbG * 8) << 9) + n;
    f16x8 h, l;
    #pragma unroll
    for (int j = 0; j < 8; ++j) {
        const float v = src[(size_t)j << 9];
        _Float16 a, b; split2(v, a, b);
        h[j] = a; l[j] = b;
    }
    *(f16x8*)(hi + (size_t)idx * 8) = h;
    *(f16x8*)(lo + (size_t)idx * 8) = l;
}

// ------------------------------------------------------------------
// Split-fp16 MFMA GEMM, fp16 hi/lo A input (LDS-staged via gload16):
// out = act(A @ Bfrag + bias). OSPL: 0 fp32 out.
// ------------------------------------------------------------------
template<int ACT>
__global__ __launch_bounds__(256, 2)
void gemm_hh(const _Float16* __restrict__ ah, const _Float16* __restrict__ al,
             const _Float16* __restrict__ bh, const _Float16* __restrict__ bl,
             const float* __restrict__ bias, int K,
             float* __restrict__ outF)
{
    __shared__ _Float16 Ah[2][2048], Al[2][2048];
    const int tid = threadIdx.x;
    const int l = tid & 63, w = tid >> 6;
    const int kb = l >> 4, lr = l & 15;
    const int m0 = blockIdx.y << 6;
    const int wn0 = (blockIdx.x << 7) + (w << 5);
    const int scr = tid & 63, sckb = tid >> 6;
    const int sbase = (tid & 192) * 8;

    f32x4 acc[4][2];
    #pragma unroll
    for (int i = 0; i < 4; ++i)
        #pragma unroll
        for (int j = 0; j < 2; ++j) acc[i][j] = (f32x4){0.f, 0.f, 0.f, 0.f};

    {
        const size_t ga = (size_t)(m0 + scr) * K + sckb * 8;
        gload16(ah + ga, Ah[0] + sbase);
        gload16(al + ga, Al[0] + sbase);
    }
    int cur = 0;
    for (int k0 = 0; k0 < K; k0 += 32) {
        __syncthreads();
        if (k0 + 32 < K) {
            const size_t ga = (size_t)(m0 + scr) * K + k0 + 32 + sckb * 8;
            gload16(ah + ga, Ah[cur ^ 1] + sbase);
            gload16(al + ga, Al[cur ^ 1] + sbase);
        }
        f16x8 fah[4], fal[4];
        #pragma unroll
        for (int i = 0; i < 4; ++i) {
            const int off = (kb * 64 + i * 16 + lr) * 8;
            fah[i] = *(const f16x8*)(Ah[cur] + off);
            fal[i] = *(const f16x8*)(Al[cur] + off);
        }
        #pragma unroll
        for (int j = 0; j < 2; ++j) {
            const size_t gb = ((size_t)(((k0 >> 3) + kb) << 9) + wn0 + j * 16 + lr) * 8;
            const f16x8 fbh = *(const f16x8*)(bh + gb);
            const f16x8 fbl = *(const f16x8*)(bl + gb);
            #pragma unroll
            for (int i = 0; i < 4; ++i) {
                acc[i][j] = __builtin_amdgcn_mfma_f32_16x16x32_f16(fah[i], fbh, acc[i][j], 0, 0, 0);
                acc[i][j] = __builtin_amdgcn_mfma_f32_16x16x32_f16(fah[i], fbl, acc[i][j], 0, 0, 0);
                acc[i][j] = __builtin_amdgcn_mfma_f32_16x16x32_f16(fal[i], fbh, acc[i][j], 0, 0, 0);
            }
        }
        cur ^= 1;
    }
    #pragma unroll
    for (int i = 0; i < 4; ++i)
        #pragma unroll
        for (int j = 0; j < 2; ++j) {
            const int n = wn0 + j * 16 + lr;
            const float bv = bias[n];
            #pragma unroll
            for (int r = 0; r < 4; ++r) {
                const int m = m0 + i * 16 + (kb << 2) + r;
                float v = acc[i][j][r] + bv;
                if (ACT) v = gelu_f(v);
                outF[((size_t)m << 9) + n] = v;
            }
        }
}

// ------------------------------------------------------------------
// Split-fp16 MFMA GEMM, fp32 A input: on-the-fly split during
// reg-staged LDS writes (one barrier/iter, dbuf).
// OSPL: 1 = split fp16 out (proj); 2 = score mode (atomicAdd
//       sum(gelu(v)*sw2[n]) into mlog4[m*4]).
// ------------------------------------------------------------------
template<int ACT, int OSPL>
__global__ __launch_bounds__(256, 2)
void gemm_fa(const float* __restrict__ A,
             const _Float16* __restrict__ bh, const _Float16* __restrict__ bl,
             const float* __restrict__ bias, int K,
             _Float16* __restrict__ oh, _Float16* __restrict__ ol,
             const float* __restrict__ sw2, float* __restrict__ mlog4)
{
    __shared__ _Float16 Ah[2][2048], Al[2][2048];
    const int tid = threadIdx.x;
    const int l = tid & 63, w = tid >> 6;
    const int kb = l >> 4, lr = l & 15;
    const int m0 = blockIdx.y << 6;
    const int wn0 = (blockIdx.x << 7) + (w << 5);
    const int sr = tid & 63, skg = tid >> 6;    // staging row / k-group

    f32x4 acc[4][2];
    #pragma unroll
    for (int i = 0; i < 4; ++i)
        #pragma unroll
        for (int j = 0; j < 2; ++j) acc[i][j] = (f32x4){0.f, 0.f, 0.f, 0.f};

    float4 a0, a1;
    {
        const float* ap = A + (size_t)(m0 + sr) * K + skg * 8;
        a0 = *(const float4*)ap; a1 = *(const float4*)(ap + 4);
    }
    const int nt = K >> 5;
    for (int kk = 0; kk < nt; ++kk) {
        const int cur = kk & 1;
        {   // split + stage regs -> LDS
            float vv[8] = {a0.x, a0.y, a0.z, a0.w, a1.x, a1.y, a1.z, a1.w};
            f16x8 h, lo8;
            #pragma unroll
            for (int q = 0; q < 8; ++q) {
                _Float16 x0, x1; split2(vv[q], x0, x1);
                h[q] = x0; lo8[q] = x1;
            }
            const int off = (skg * 64 + sr) * 8;
            *(f16x8*)(Ah[cur] + off) = h;
            *(f16x8*)(Al[cur] + off) = lo8;
        }
        __syncthreads();
        if (kk + 1 < nt) {
            const float* ap = A + (size_t)(m0 + sr) * K + (kk + 1) * 32 + skg * 8;
            a0 = *(const float4*)ap; a1 = *(const float4*)(ap + 4);
        }
        f16x8 fah[4], fal[4];
        #pragma unroll
        for (int i = 0; i < 4; ++i) {
            const int off = (kb * 64 + i * 16 + lr) * 8;
            fah[i] = *(const f16x8*)(Ah[cur] + off);
            fal[i] = *(const f16x8*)(Al[cur] + off);
        }
        #pragma unroll
        for (int j = 0; j < 2; ++j) {
            const size_t gb = ((size_t)((kk * 4 + kb) << 9) + wn0 + j * 16 + lr) * 8;
            const f16x8 fbh = *(const f16x8*)(bh + gb);
            const f16x8 fbl = *(const f16x8*)(bl + gb);
            #pragma unroll
            for (int i = 0; i < 4; ++i) {
                acc[i][j] = __builtin_amdgcn_mfma_f32_16x16x32_f16(fah[i], fbh, acc[i][j], 0, 0, 0);
                acc[i][j] = __builtin_amdgcn_mfma_f32_16x16x32_f16(fah[i], fbl, acc[i][j], 0, 0, 0);
                acc[i][j] = __builtin_amdgcn_mfma_f32_16x16x32_f16(fal[i], fbh, acc[i][j], 0, 0, 0);
            }
        }
    }
    #pragma unroll
    for (int i = 0; i < 4; ++i) {
        float sacc[4] = {0.f, 0.f, 0.f, 0.f};
        #pragma unroll
        for (int j = 0; j < 2; ++j) {
            const int n = wn0 + j * 16 + lr;
            const float bv = bias[n];
            const float swv = (OSPL == 2) ? sw2[n] : 0.f;
            #pragma unroll
            for (int r = 0; r < 4; ++r) {
                const int m = m0 + i * 16 + (kb << 2) + r;
                float v = acc[i][j][r] + bv;
                if (ACT) v = gelu_f(v);
                if (OSPL == 2) {
                    sacc[r] = fmaf(v, swv, sacc[r]);
                } else {
                    _Float16 vh, vl; split2(v, vh, vl);
                    oh[((size_t)m << 9) + n] = vh;
                    ol[((size_t)m << 9) + n] = vl;
                }
            }
        }
        if (OSPL == 2) {
            #pragma unroll
            for (int r = 0; r < 4; ++r) {
                float s = sacc[r];
                s += __shfl_xor(s, 1, 64);
                s += __shfl_xor(s, 2, 64);
                s += __shfl_xor(s, 4, 64);
                s += __shfl_xor(s, 8, 64);
                if (lr == 0) {
                    const int m = m0 + i * 16 + (kb << 2) + r;
                    atomicAdd(&mlog4[m << 2], s);
                }
            }
        }
    }
}

// ------------------------------------------------------------------
// Fused expert v7: 1m x 8n wave grid -- each weight byte read exactly
// once per block (halves L2 weight traffic vs 2m x 4n); X frags are
// identical across waves (L1 broadcast). Barrier-free K-loops, one
// barrier between H-write and H-read.
// grid = (64, 8), y = expert (expert-major L2 behavior, R5/R6-proven).
// LDS 128 KB (H split-fp16 subtiled) -> 1 block/CU, 8 waves.
// ------------------------------------------------------------------
__global__ __launch_bounds__(512, 2)
void fused_expert7(const _Float16* __restrict__ xh, const _Float16* __restrict__ xl,
                   const _Float16* __restrict__ w1h, const _Float16* __restrict__ w1l,
                   const _Float16* __restrict__ w2h, const _Float16* __restrict__ w2l,
                   const float* __restrict__ eb1, const float* __restrict__ rw,
                   float* __restrict__ mixed)
{
    __shared__ _Float16 Hh[32768], Hl[32768];     // [64 kgrp][64 row][8]
    const int tid = threadIdx.x;
    const int w = tid >> 6, l = tid & 63;
    const int kb = l >> 4, lr = l & 15;
    const int e = blockIdx.y;
    const int m0 = blockIdx.x << 6;
    const int wn0 = w << 6;                       // 64-wide n slice per wave

    const _Float16* w1he = w1h + ((size_t)e << 18);
    const _Float16* w1le = w1l + ((size_t)e << 18);
    const _Float16* w2he = w2h + ((size_t)e << 18);
    const _Float16* w2le = w2l + ((size_t)e << 18);

    // ---- stage 1: acc1 = X @ W1e ----
    f32x4 acc1[4][4];
    #pragma unroll
    for (int i = 0; i < 4; ++i)
        #pragma unroll
        for (int j = 0; j < 4; ++j) acc1[i][j] = (f32x4){0.f, 0.f, 0.f, 0.f};

    #pragma unroll
    for (int kk = 0; kk < 16; ++kk) {
        f16x8 fxh[4], fxl[4];
        #pragma unroll
        for (int i = 0; i < 4; ++i) {
            const size_t ga = ((size_t)(m0 + i * 16 + lr) << 9) + kk * 32 + kb * 8;
            fxh[i] = *(const f16x8*)(xh + ga);
            fxl[i] = *(const f16x8*)(xl + ga);
        }
        f16x8 wbh[4], wbl[4];
        #pragma unroll
        for (int j = 0; j < 4; ++j) {
            const int n = wn0 + j * 16 + lr;
            const size_t gb = ((size_t)((kk * 4 + kb) << 9) + n) * 8;
            wbh[j] = *(const f16x8*)(w1he + gb);
            wbl[j] = *(const f16x8*)(w1le + gb);
        }
        #pragma unroll
        for (int j = 0; j < 4; ++j)
            #pragma unroll
            for (int i = 0; i < 4; ++i) {
                acc1[i][j] = __builtin_amdgcn_mfma_f32_16x16x32_f16(fxh[i], wbh[j], acc1[i][j], 0, 0, 0);
                acc1[i][j] = __builtin_amdgcn_mfma_f32_16x16x32_f16(fxh[i], wbl[j], acc1[i][j], 0, 0, 0);
                acc1[i][j] = __builtin_amdgcn_mfma_f32_16x16x32_f16(fxl[i], wbh[j], acc1[i][j], 0, 0, 0);
            }
    }
    // ---- epilogue 1: gelu+bias+route-scale -> H (split fp16, subtiled) ----
    #pragma unroll
    for (int i = 0; i < 4; ++i)
        #pragma unroll
        for (int j = 0; j < 4; ++j) {
            const int n = wn0 + j * 16 + lr;
            const float bv = eb1[(e << 9) + n];
            #pragma unroll
            for (int r = 0; r < 4; ++r) {
                const int ri = i * 16 + (kb << 2) + r;
                const float v = gelu_f(acc1[i][j][r] + bv) * rw[((size_t)(m0 + ri) << 3) + e];
                _Float16 vh, vl; split2(v, vh, vl);
                const int off = ((n >> 3) * 64 + ri) * 8 + (n & 7);
                Hh[off] = vh; Hl[off] = vl;
            }
        }
    __syncthreads();   // the ONLY barrier: H fully written before reads

    // ---- stage 2: acc2 = H @ W2e ----
    f32x4 acc2[4][4];
    #pragma unroll
    for (int i = 0; i < 4; ++i)
        #pragma unroll
        for (int j = 0; j < 4; ++j) acc2[i][j] = (f32x4){0.f, 0.f, 0.f, 0.f};

    #pragma unroll
    for (int kk = 0; kk < 16; ++kk) {
        f16x8 fah[4], fal[4];
        #pragma unroll
        for (int i = 0; i < 4; ++i) {
            const int off = ((kk * 4 + kb) * 64 + i * 16 + lr) * 8;
            fah[i] = *(const f16x8*)(Hh + off);
            fal[i] = *(const f16x8*)(Hl + off);
        }
        f16x8 qbh[4], qbl[4];
        #pragma unroll
        for (int j = 0; j < 4; ++j) {
            const int n = wn0 + j * 16 + lr;
            const size_t gb = ((size_t)((kk * 4 + kb) << 9) + n) * 8;
            qbh[j] = *(const f16x8*)(w2he + gb);
            qbl[j] = *(const f16x8*)(w2le + gb);
        }
        #pragma unroll
        for (int j = 0; j < 4; ++j)
            #pragma unroll
            for (int i = 0; i < 4; ++i) {
                acc2[i][j] = __builtin_amdgcn_mfma_f32_16x16x32_f16(fah[i], qbh[j], acc2[i][j], 0, 0, 0);
                acc2[i][j] = __builtin_amdgcn_mfma_f32_16x16x32_f16(fah[i], qbl[j], acc2[i][j], 0, 0, 0);
                acc2[i][j] = __builtin_amdgcn_mfma_f32_16x16x32_f16(fal[i], qbh[j], acc2[i][j], 0, 0, 0);
            }
    }
    #pragma unroll
    for (int i = 0; i < 4; ++i)
        #pragma unroll
        for (int j = 0; j < 4; ++j) {
            const int n = wn0 + j * 16 + lr;
            #pragma unroll
            for (int r = 0; r < 4; ++r) {
                const int m = m0 + i * 16 + (kb << 2) + r;
                atomicAdd(&mixed[((size_t)m << 9) + n], acc2[i][j][r]);
            }
        }
}

// ------------------------------------------------------------------
// mixed init: mixed[m][n] = sum_e rw[m][e] * eb2[e][n]. grid = 2048
// ------------------------------------------------------------------
__global__ __launch_bounds__(256)
void init_mixed(const float* __restrict__ rw, const float* __restrict__ eb2,
                float* __restrict__ mixed)
{
    const int idx = blockIdx.x * 256 + threadIdx.x;
    const int m = idx >> 7, n4 = (idx & 127) << 2;
    float rwv[8];
    #pragma unroll
    for (int e = 0; e < 8; ++e) rwv[e] = rw[(m << 3) + e];
    float4 o = {0.f, 0.f, 0.f, 0.f};
    #pragma unroll
    for (int e = 0; e < 8; ++e) {
        const float4 b = *(const float4*)(eb2 + (e << 9) + n4);
        o.x = fmaf(rwv[e], b.x, o.x); o.y = fmaf(rwv[e], b.y, o.y);
        o.z = fmaf(rwv[e], b.z, o.z); o.w = fmaf(rwv[e], b.w, o.w);
    }
    *(float4*)(mixed + ((size_t)m << 9) + n4) = o;
}

// ------------------------------------------------------------------
// Router softmax
// ------------------------------------------------------------------
__global__ __launch_bounds__(256)
void router_kernel(const float* __restrict__ t,
                   const float* __restrict__ rw2,
                   const float* __restrict__ rb2,
                   float* __restrict__ route_w)
{
    __shared__ float s[512 * 9];
    const int tid = threadIdx.x;
    for (int idx = tid; idx < 4096; idx += 256)
        s[(idx >> 3) * 9 + (idx & 7)] = rw2[idx];
    __syncthreads();
    const int lane = tid & 63;
    const int tok = (blockIdx.x << 2) + (tid >> 6);
    const float* tp = t + ((size_t)tok << 9);
    float acc[8] = {};
    #pragma unroll
    for (int kq = 0; kq < 8; ++kq) {
        const int k = (kq << 6) + lane;
        const float tv = tp[k];
        #pragma unroll
        for (int e = 0; e < 8; ++e)
            acc[e] = fmaf(tv, s[k * 9 + e], acc[e]);
    }
    #pragma unroll
    for (int e = 0; e < 8; ++e)
        #pragma unroll
        for (int off = 32; off; off >>= 1)
            acc[e] += __shfl_xor(acc[e], off, 64);
    float mx = -1e30f;
    #pragma unroll
    for (int e = 0; e < 8; ++e) { acc[e] += rb2[e]; mx = fmaxf(mx, acc[e]); }
    float sum = 0.f;
    #pragma unroll
    for (int e = 0; e < 8; ++e) { acc[e] = expf(acc[e] - mx); sum += acc[e]; }
    const float inv = 1.0f / sum;
    if (lane == 0) {
        #pragma unroll
        for (int e = 0; e < 8; ++e) route_w[(tok << 3) + e] = acc[e] * inv;
    }
}

// ------------------------------------------------------------------
// Final: top-2 + masked softmax + blend + LayerNorm, one block/token.
// ------------------------------------------------------------------
__global__ __launch_bounds__(256)
void final_kernel(const float* __restrict__ mixedb,
                  const float* __restrict__ mlog,
                  const float* __restrict__ sb2,
                  const float* __restrict__ g,
                  const float* __restrict__ bta,
                  float* __restrict__ out)
{
    const int tok = blockIdx.x, tid = threadIdx.x;
    float v[4];
    #pragma unroll
    for (int m = 0; m < 4; ++m) v[m] = mlog[(tok << 2) + m] + sb2[0];
    int i1 = 0;
    #pragma unroll
    for (int m = 1; m < 4; ++m) if (v[m] > v[i1]) i1 = m;
    int i2 = (i1 == 0) ? 1 : 0;
    for (int m = i2 + 1; m < 4; ++m) if (m != i1 && v[m] > v[i2]) i2 = m;
    const float e2 = expf(v[i2] - v[i1]);
    const float winv = 1.0f / (1.0f + e2);
    const float w1 = winv, w2 = e2 * winv;
    const float* p1 = mixedb + (((size_t)i1 * TOK + tok) << 9);
    const float* p2 = mixedb + (((size_t)i2 * TOK + tok) << 9);
    const int h0 = tid, h1 = tid + 256;
    const float c0 = w1 * p1[h0] + w2 * p2[h0];
    const float c1 = w1 * p1[h1] + w2 * p2[h1];
    float s = c0 + c1, sq = c0 * c0 + c1 * c1;
    #pragma unroll
    for (int off = 32; off; off >>= 1) {
        s += __shfl_xor(s, off, 64);
        sq += __shfl_xor(sq, off, 64);
    }
    __shared__ float red[8];
    const int wv = tid >> 6, ln = tid & 63;
    if (ln == 0) { red[wv] = s; red[4 + wv] = sq; }
    __syncthreads();
    s = red[0] + red[1] + red[2] + red[3];
    sq = red[4] + red[5] + red[6] + red[7];
    const float mu = s * (1.0f / 512.0f);
    const float var = sq * (1.0f / 512.0f) - mu * mu;
    const float r = 1.0f / sqrtf(var + 1e-5f);
    out[((size_t)tok << 9) + h0] = (c0 - mu) * r * g[h0] + bta[h0];
    out[((size_t)tok << 9) + h1] = (c1 - mu) * r * g[h1] + bta[h1];
}

extern "C" void kernel_launch(void* const* d_in, const int* in_sizes, int n_in,
                              void* d_out, int out_size, void* d_ws, size_t ws_size,
                              hipStream_t stream)
{
    (void)in_sizes; (void)n_in; (void)out_size; (void)ws_size;
    const float* ew1  = (const float*)d_in[12];
    const float* eb1  = (const float*)d_in[13];
    const float* ew2  = (const float*)d_in[14];
    const float* eb2  = (const float*)d_in[15];
    const float* rw1  = (const float*)d_in[16];
    const float* rb1  = (const float*)d_in[17];
    const float* rw2  = (const float*)d_in[18];
    const float* rb2  = (const float*)d_in[19];
    const float* sw1  = (const float*)d_in[20];
    const float* sb1  = (const float*)d_in[21];
    const float* sw2  = (const float*)d_in[22];
    const float* sb2  = (const float*)d_in[23];
    const float* ln_g = (const float*)d_in[24];
    const float* ln_b = (const float*)d_in[25];
    const int KD[4] = {1024, 64, 768, 512};

    // ---- workspace layout ----
    char* p = (char*)d_ws;
    auto alloc = [&](size_t bytes) {
        void* r = (void*)p;
        p += (bytes + 255) & ~(size_t)255;
        return r;
    };
    float*     mixedb  = (float*)alloc((size_t)4 * TOK * HD * 4);
    float*     scratch = (float*)alloc((size_t)TOK * HD * 4);   // t
    float*     route_w = (float*)alloc((size_t)TOK * 8 * 4);
    float*     mlog    = (float*)alloc((size_t)TOK * 4 * 4);
    _Float16*  xh      = (_Float16*)alloc((size_t)TOK * HD * 2);
    _Float16*  xl      = (_Float16*)alloc((size_t)TOK * HD * 2);
    _Float16*  pwh     = (_Float16*)alloc((size_t)1024 * HD * 2);
    _Float16*  pwl     = (_Float16*)alloc((size_t)1024 * HD * 2);
    _Float16*  rw1h    = (_Float16*)alloc((size_t)HD * HD * 2);
    _Float16*  rw1l    = (_Float16*)alloc((size_t)HD * HD * 2);
    _Float16*  sw1h    = (_Float16*)alloc((size_t)HD * HD * 2);
    _Float16*  sw1l    = (_Float16*)alloc((size_t)HD * HD * 2);
    _Float16*  w1h     = (_Float16*)alloc((size_t)8 * HD * HD * 2);
    _Float16*  w1l     = (_Float16*)alloc((size_t)8 * HD * HD * 2);
    _Float16*  w2h     = (_Float16*)alloc((size_t)8 * HD * HD * 2);
    _Float16*  w2l     = (_Float16*)alloc((size_t)8 * HD * HD * 2);

    // mlog accumulated via atomics -> zero it (ws is re-poisoned every call)
    hipMemsetAsync(mlog, 0, (size_t)TOK * 4 * sizeof(float), stream);

    // ---- weight prep (frag layout splits) ----
    split_w_kernel<<<dim3(1024), 256, 0, stream>>>(ew1, w1h, w1l);
    split_w_kernel<<<dim3(1024), 256, 0, stream>>>(ew2, w2h, w2l);
    split_w_kernel<<<dim3(128), 256, 0, stream>>>(rw1, rw1h, rw1l);
    split_w_kernel<<<dim3(128), 256, 0, stream>>>(sw1, sw1h, sw1l);

    for (int mod = 0; mod < 4; ++mod) {
        const float* feat = (const float*)d_in[mod * 3 + 0];
        const float* pw   = (const float*)d_in[mod * 3 + 1];
        const float* pb   = (const float*)d_in[mod * 3 + 2];
        float* mixm = mixedb + (size_t)mod * TOK * HD;
        const int K = KD[mod];

        // pw split for this modality
        split_w_kernel<<<dim3(K / 4), 256, 0, stream>>>(pw, pwh, pwl);
        // x = feat @ pw + pb  (fp32 A, on-the-fly split) -> xh/xl
        gemm_fa<0, 1><<<dim3(4, 64), 256, 0, stream>>>(
            feat, pwh, pwl, pb, K, xh, xl, nullptr, nullptr);
        // t = gelu(x @ rw1 + rb1)
        gemm_hh<1><<<dim3(4, 64), 256, 0, stream>>>(
            xh, xl, rw1h, rw1l, rb1, HD, scratch);
        // route_w = softmax(t @ rw2 + rb2)
        router_kernel<<<dim3(TOK / 4), 256, 0, stream>>>(scratch, rw2, rb2, route_w);
        // mixed = sum_e rw*eb2, then fused experts accumulate
        init_mixed<<<dim3(TOK * HD / 4 / 256), 256, 0, stream>>>(route_w, eb2, mixm);
        fused_expert7<<<dim3(64, 8), 512, 0, stream>>>(
            xh, xl, w1h, w1l, w2h, w2l, eb1, route_w, mixm);
        // mlog[:,mod] = gelu(mixed @ sw1 + sb1) . sw2  (fp32 A, fused score)
        gemm_fa<1, 2><<<dim3(4, 64), 256, 0, stream>>>(
            mixm, sw1h, sw1l, sb1, HD, nullptr, nullptr, sw2, mlog + mod);
    }
    final_kernel<<<dim3(TOK), 256, 0, stream>>>(mixedb, mlog, sb2, ln_g, ln_b, (float*)d_out);
}